// Round 10
// baseline (713.700 us; speedup 1.0000x reference)
//
#include <hip/hip_runtime.h>
#include <math.h>

#define NN 100000
#define NE 1600000
#define NG 256
#define D 128
#define EPS 1e-5f
#define MAXDEG 64
#define EPB 12800
#define SLICE_N 12500
#define GRID_FILL 1000          // (NE/EPB)*8
#define GRID_CAST 6250          // NN*D/8/256
#define GRID_TW 32
#define GRID_GEMM 782           // ceil(NN/128)

typedef __attribute__((ext_vector_type(8))) short s16x8;
typedef __attribute__((ext_vector_type(4))) float f32x4;

__device__ __forceinline__ ushort f2b(float f) {
    uint u = __float_as_uint(f);
    uint r = (u + 0x7fffu + ((u >> 16) & 1u)) >> 16;   // RNE
    return (ushort)r;
}
__device__ __forceinline__ float blo(uint u) { return __uint_as_float(u << 16); }
__device__ __forceinline__ float bhi(uint u) { return __uint_as_float(u & 0xFFFF0000u); }

// W-LDS byte swizzle: XOR row&7 into bits 4-6 of the intra-row offset (involution)
#define SWZW(lin) ((lin) ^ ((((lin) >> 8) & 7) << 4))

// ============ prep: fill (XCD-sliced) + cast x->bf16 + weight transpose, one dispatch ============
__global__ __launch_bounds__(256) void prep(const int* __restrict__ esrc, const int* __restrict__ edst,
                                            int* __restrict__ cursor, int* __restrict__ slots,
                                            const float* __restrict__ x, ushort* __restrict__ xb,
                                            const float* __restrict__ w1a, const float* __restrict__ w1b,
                                            const float* __restrict__ w2a, const float* __restrict__ w2b,
                                            ushort* __restrict__ Wt) {
    int b = blockIdx.x;
    if (b < GRID_FILL) {
        const int slice = b & 7;
        const int chunk = b >> 3;
        const int lo = slice * SLICE_N, hi = lo + SLICE_N;
        const int ebase = chunk * EPB;
        for (int i = threadIdx.x; i < EPB / 4; i += 256) {
            int e = ebase + i * 4;
            int4 s = *(const int4*)(esrc + e);
            int4 d = *(const int4*)(edst + e);
            if (d.x >= lo && d.x < hi) { int p = atomicAdd(&cursor[d.x], 1); slots[(d.x << 6) | (p & 63)] = s.x; }
            if (d.y >= lo && d.y < hi) { int p = atomicAdd(&cursor[d.y], 1); slots[(d.y << 6) | (p & 63)] = s.y; }
            if (d.z >= lo && d.z < hi) { int p = atomicAdd(&cursor[d.z], 1); slots[(d.z << 6) | (p & 63)] = s.z; }
            if (d.w >= lo && d.w < hi) { int p = atomicAdd(&cursor[d.w], 1); slots[(d.w << 6) | (p & 63)] = s.w; }
        }
    } else if (b < GRID_FILL + GRID_CAST) {
        int i = (b - GRID_FILL) * 256 + threadIdx.x;
        if (i * 8 < NN * D) {
            float4 v0 = *(const float4*)(x + i * 8);
            float4 v1 = *(const float4*)(x + i * 8 + 4);
            ushort o[8] = {f2b(v0.x), f2b(v0.y), f2b(v0.z), f2b(v0.w),
                           f2b(v1.x), f2b(v1.y), f2b(v1.z), f2b(v1.w)};
            *(uint4*)(xb + i * 8) = *(uint4*)o;
        }
    } else {
        int by = b - GRID_FILL - GRID_CAST;      // 0..31
        int wsel = by >> 3, bx = by & 7;
        const float* W = (wsel == 0) ? w1a : (wsel == 1) ? w1b : (wsel == 2) ? w2a : w2b;
        ushort* T = Wt + wsel * 16384;
        for (int i = bx * 256 + threadIdx.x; i < 16384; i += 8 * 256) {
            int k = i >> 7, cc = i & 127;
            T[(cc << 7) | k] = f2b(W[i]);
        }
    }
}

// ============ gather, 8 rows in flight, optional fused BN+ReLU ============
template <int FUSE_BN>
__global__ __launch_bounds__(256) void gather_slots(ushort* __restrict__ out, const ushort* __restrict__ feat,
                                                    const int* __restrict__ deg, const int* __restrict__ slots,
                                                    const float* __restrict__ scale, const float* __restrict__ shift) {
    int node = __builtin_amdgcn_readfirstlane(blockIdx.x * 4 + (threadIdx.x >> 6));
    if (node >= NN) return;
    int lane = threadIdx.x & 63;
    int n = deg[node];
    n = (n > MAXDEG) ? MAXDEG : n;
    const int* sl = slots + (node << 6);
    float scx = 1.f, scy = 1.f, shx = 0.f, shy = 0.f;
    if (FUSE_BN) {
        float2 sc = *(const float2*)(scale + lane * 2);
        float2 sh = *(const float2*)(shift + lane * 2);
        scx = sc.x; scy = sc.y; shx = sh.x; shy = sh.y;
    }
    uint ub = *(const uint*)(feat + node * D + lane * 2);
    float axv[8], ayv[8];
#pragma unroll
    for (int j = 0; j < 8; ++j) { axv[j] = 0.f; ayv[j] = 0.f; }
    if (FUSE_BN) {
        axv[0] = fmaxf(fmaf(blo(ub), scx, shx), 0.f);
        ayv[0] = fmaxf(fmaf(bhi(ub), scy, shy), 0.f);
    } else {
        axv[0] = blo(ub); ayv[0] = bhi(ub);
    }
    int e = 0;
    for (; e + 7 < n; e += 8) {
        uint u[8];
#pragma unroll
        for (int j = 0; j < 8; ++j) u[j] = *(const uint*)(feat + sl[e + j] * D + lane * 2);
#pragma unroll
        for (int j = 0; j < 8; ++j) {
            if (FUSE_BN) {
                axv[j] += fmaxf(fmaf(blo(u[j]), scx, shx), 0.f);
                ayv[j] += fmaxf(fmaf(bhi(u[j]), scy, shy), 0.f);
            } else {
                axv[j] += blo(u[j]); ayv[j] += bhi(u[j]);
            }
        }
    }
    for (; e < n; ++e) {
        uint u0 = *(const uint*)(feat + sl[e] * D + lane * 2);
        if (FUSE_BN) {
            axv[0] += fmaxf(fmaf(blo(u0), scx, shx), 0.f);
            ayv[0] += fmaxf(fmaf(bhi(u0), scy, shy), 0.f);
        } else {
            axv[0] += blo(u0); ayv[0] += bhi(u0);
        }
    }
    float ax = ((axv[0] + axv[1]) + (axv[2] + axv[3])) + ((axv[4] + axv[5]) + (axv[6] + axv[7]));
    float ay = ((ayv[0] + ayv[1]) + (ayv[2] + ayv[3])) + ((ayv[4] + ayv[5]) + (ayv[6] + ayv[7]));
    uint o = (uint)f2b(ax) | ((uint)f2b(ay) << 16);
    *(uint*)(out + node * D + lane * 2) = o;
}

// ============ fused dual GEMM + BN partials; W staged in LDS ============
// 512 thr = 8 waves, 128 rows/block, 16 rows/wave. W read via ds_read_b128 (swizzled).
// T/H tile fragment layout: off(row,k) = (k>>5)<<13 | ((k>>3)&3)<<11 | ((row^((k>>3)&7))<<4) | (k&7)<<1
__global__ __launch_bounds__(512, 4) void gemm_dual(const ushort* __restrict__ G,
                                                    const ushort* __restrict__ Wta, const float* __restrict__ ba,
                                                    const ushort* __restrict__ Wtb, const float* __restrict__ bb,
                                                    ushort* __restrict__ H, float4* __restrict__ stat, int nrows) {
    __shared__ ushort wbuf[16384];   // 32 KB swizzled W (Wa then Wb)
    __shared__ ushort tbuf[16384];   // 32 KB T then H, fragment layout
    __shared__ float4 red[8][64];
    char* wb = (char*)wbuf;
    char* tb = (char*)tbuf;

    const int tid = threadIdx.x;
    const int lane = tid & 63;
    const int wave = tid >> 6;          // 0..7
    const int lr = lane & 15;
    const int kg = lane >> 4;
    const int rloc = wave * 16 + lr;    // 0..127
    const int grow = blockIdx.x * 128 + rloc;
    const int growc = (grow > nrows - 1) ? (nrows - 1) : grow;
    const int wrow = lr * 256;          // W row base (row = ct*16+lr; ct*16 ≡ 0 mod 8)
    const int wswz = (lr & 7) << 4;     // XOR mask for bits 4-6 of the intra-row offset

    // ---- prefetch A fragments (coalesced global) ----
    const ushort* gp = G + growc * D + kg * 8;
    s16x8 af0 = *(const s16x8*)(gp);
    s16x8 af1 = *(const s16x8*)(gp + 32);
    s16x8 af2 = *(const s16x8*)(gp + 64);
    s16x8 af3 = *(const s16x8*)(gp + 96);

    // ---- stage Wa -> LDS (swizzled; 512 thr x 64 B) ----
#pragma unroll
    for (int i = 0; i < 4; ++i) {
        int lin = i * 8192 + tid * 16;
        uint4 v = *(const uint4*)((const char*)Wta + lin);
        *(uint4*)(wb + SWZW(lin)) = v;
    }
    __syncthreads();

    f32x4 acc[8];
#pragma unroll
    for (int ct = 0; ct < 8; ++ct) acc[ct] = (f32x4)0.f;

    // ---- stage 1: acc = G @ Wa (W from LDS; full offset XOR!) ----
#pragma unroll
    for (int ks = 0; ks < 4; ++ks) {
        s16x8 af = (ks == 0) ? af0 : (ks == 1) ? af1 : (ks == 2) ? af2 : af3;
        const int wofs = (kg * 16 + ks * 64) ^ wswz;
#pragma unroll
        for (int ct = 0; ct < 8; ++ct) {
            s16x8 a = *(const s16x8*)(wb + wrow + ct * 4096 + wofs);
            acc[ct] = __builtin_amdgcn_mfma_f32_16x16x32_bf16(a, af, acc[ct], 0, 0, 0);
        }
    }

    // ---- T = relu(acc + ba) -> tbuf ----
#pragma unroll
    for (int ct = 0; ct < 8; ++ct) {
        int k0 = ct * 16 + kg * 4;
        float4 bv = *(const float4*)(ba + k0);
        float o0 = fmaxf(acc[ct][0] + bv.x, 0.f);
        float o1 = fmaxf(acc[ct][1] + bv.y, 0.f);
        float o2 = fmaxf(acc[ct][2] + bv.z, 0.f);
        float o3 = fmaxf(acc[ct][3] + bv.w, 0.f);
        ushort pk[4] = {f2b(o0), f2b(o1), f2b(o2), f2b(o3)};
        int kb = k0 >> 3;
        int off = ((k0 >> 5) << 13) | ((kb & 3) << 11) | ((rloc ^ (kb & 7)) << 4) | ((k0 & 7) << 1);
        *(uint2*)(tb + off) = *(const uint2*)pk;
    }
    __syncthreads();   // stage-1 W reads + T writes complete

    // ---- stage Wb into wbuf ----
#pragma unroll
    for (int i = 0; i < 4; ++i) {
        int lin = i * 8192 + tid * 16;
        uint4 v = *(const uint4*)((const char*)Wtb + lin);
        *(uint4*)(wb + SWZW(lin)) = v;
    }
    // T fragments (tbuf stable until after next barrier)
    s16x8 bf[4];
#pragma unroll
    for (int ks = 0; ks < 4; ++ks) {
        int kb = ks * 4 + kg;
        bf[ks] = *(const s16x8*)(tb + ((ks << 13) | (kg << 11) | ((rloc ^ (kb & 7)) << 4)));
    }
    __syncthreads();   // Wb staged; all bf reads done

    // ---- stage 2: acc = T @ Wb ----
#pragma unroll
    for (int ct = 0; ct < 8; ++ct) acc[ct] = (f32x4)0.f;
#pragma unroll
    for (int ks = 0; ks < 4; ++ks) {
        const int wofs = (kg * 16 + ks * 64) ^ wswz;
#pragma unroll
        for (int ct = 0; ct < 8; ++ct) {
            s16x8 a = *(const s16x8*)(wb + wrow + ct * 4096 + wofs);
            acc[ct] = __builtin_amdgcn_mfma_f32_16x16x32_bf16(a, bf[ks], acc[ct], 0, 0, 0);
        }
    }

    // ---- H = acc + bb -> global + tbuf (zeros for pad rows) ----
#pragma unroll
    for (int ct = 0; ct < 8; ++ct) {
        int k0 = ct * 16 + kg * 4;
        float4 bv = *(const float4*)(bb + k0);
        uint2 pk2 = make_uint2(0u, 0u);
        if (grow < nrows) {
            float o0 = acc[ct][0] + bv.x;
            float o1 = acc[ct][1] + bv.y;
            float o2 = acc[ct][2] + bv.z;
            float o3 = acc[ct][3] + bv.w;
            ushort pk[4] = {f2b(o0), f2b(o1), f2b(o2), f2b(o3)};
            pk2 = *(const uint2*)pk;
            *(uint2*)(H + grow * D + k0) = pk2;
        }
        int kb = k0 >> 3;
        int off = ((k0 >> 5) << 13) | ((kb & 3) << 11) | ((rloc ^ (kb & 7)) << 4) | ((k0 & 7) << 1);
        *(uint2*)(tb + off) = pk2;
    }
    __syncthreads();

    // ---- column partials over the 128-row tile -> plain stores (no atomics) ----
    {
        int c2 = tid & 63;                      // feature pair 2*c2, 2*c2+1
        int rg = tid >> 6;                      // 0..7 -> 16 rows each
        int k = c2 * 2;
        int kb = k >> 3;
        int base = ((k >> 5) << 13) | ((kb & 3) << 11) | ((k & 7) << 1);
        float s0 = 0.f, q0 = 0.f, s1 = 0.f, q1 = 0.f;
#pragma unroll 4
        for (int i = 0; i < 16; ++i) {
            int row = rg * 16 + i;
            uint u = *(const uint*)(tb + base + ((row ^ (kb & 7)) << 4));
            float lo = blo(u), hi = bhi(u);
            s0 += lo; q0 += lo * lo; s1 += hi; q1 += hi * hi;
        }
        red[rg][c2] = make_float4(s0, q0, s1, q1);
    }
    __syncthreads();
    if (tid < 64) {
        float4 r0 = red[0][tid], r1 = red[1][tid], r2 = red[2][tid], r3 = red[3][tid];
        float4 r4 = red[4][tid], r5 = red[5][tid], r6 = red[6][tid], r7 = red[7][tid];
        float4 o;
        o.x = ((r0.x + r1.x) + (r2.x + r3.x)) + ((r4.x + r5.x) + (r6.x + r7.x));
        o.y = ((r0.y + r1.y) + (r2.y + r3.y)) + ((r4.y + r5.y) + (r6.y + r7.y));
        o.z = ((r0.z + r1.z) + (r2.z + r3.z)) + ((r4.z + r5.z) + (r6.z + r7.z));
        o.w = ((r0.w + r1.w) + (r2.w + r3.w)) + ((r4.w + r5.w) + (r6.w + r7.w));
        stat[blockIdx.x * 64 + tid] = o;
    }
}

// ============ reduce partials + finalize scale/shift ============
__global__ __launch_bounds__(64) void bn_finalize(const float4* __restrict__ stat, int nblk,
                                                  const float* __restrict__ gamma, const float* __restrict__ beta,
                                                  float* __restrict__ scale, float* __restrict__ shift, int nrows) {
    int t = threadIdx.x;
    double s0 = 0, q0 = 0, s1 = 0, q1 = 0;
    for (int b = 0; b < nblk; ++b) {
        float4 v = stat[b * 64 + t];
        s0 += v.x; q0 += v.y; s1 += v.z; q1 += v.w;
    }
    int f0 = 2 * t, f1 = 2 * t + 1;
    double m0 = s0 / nrows, v0 = q0 / nrows - m0 * m0;
    double m1 = s1 / nrows, v1 = q1 / nrows - m1 * m1;
    float sc0 = gamma[f0] * rsqrtf((float)v0 + EPS);
    float sc1 = gamma[f1] * rsqrtf((float)v1 + EPS);
    scale[f0] = sc0; shift[f0] = beta[f0] - (float)m0 * sc0;
    scale[f1] = sc1; shift[f1] = beta[f1] - (float)m1 * sc1;
}

// ============ pool: partial sums into pooled[g][f] via run-flush atomics ============
__global__ __launch_bounds__(256) void pool_partial(const ushort* __restrict__ h, const int* __restrict__ batch,
                                                    const float* __restrict__ scale, const float* __restrict__ shift,
                                                    float* __restrict__ pooled) {
    int wave = threadIdx.x >> 6;
    int lane = threadIdx.x & 63;
    int r0 = blockIdx.x * 256 + wave * 64;
    if (r0 >= NN) return;
    int f2 = lane * 2;
    float2 sc = *(const float2*)(scale + f2);
    float2 sh = *(const float2*)(shift + f2);
    float ax = 0.f, ay = 0.f;
    int cur = -1;
    int rend = r0 + 64; if (rend > NN) rend = NN;
    for (int r = r0; r < rend; ++r) {
        int g = batch[r];
        if (g != cur) {
            if (cur >= 0) {
                atomicAdd(&pooled[cur * D + f2], ax);
                atomicAdd(&pooled[cur * D + f2 + 1], ay);
            }
            cur = g; ax = 0.f; ay = 0.f;
        }
        uint u = *(const uint*)(h + r * D + f2);
        ax += fmaxf(fmaf(blo(u), sc.x, sh.x), 0.f);
        ay += fmaxf(fmaf(bhi(u), sc.y, sh.y), 0.f);
    }
    if (cur >= 0) {
        atomicAdd(&pooled[cur * D + f2], ax);
        atomicAdd(&pooled[cur * D + f2 + 1], ay);
    }
}

__device__ __forceinline__ int lower_bound_i(const int* a, int n, int v) {
    int lo = 0, hi = n;
    while (lo < hi) {
        int m = (lo + hi) >> 1;
        if (a[m] < v) lo = m + 1; else hi = m;
    }
    return lo;
}

__global__ __launch_bounds__(256) void head(const float* __restrict__ pooled, const int* __restrict__ batch,
                                            const float* __restrict__ wl, const float* __restrict__ bl,
                                            float* __restrict__ out) {
    int g = blockIdx.x * 256 + threadIdx.x;
    if (g >= NG) return;
    int lo = lower_bound_i(batch, NN, g);
    int hi = lower_bound_i(batch, NN, g + 1);
    float inv = 1.f / fmaxf((float)(hi - lo), 1.f);
    float logits[7];
#pragma unroll
    for (int c = 0; c < 7; ++c) logits[c] = bl[c];
    for (int k = 0; k < D; ++k) {
        float p = pooled[g * D + k] * inv;
#pragma unroll
        for (int c = 0; c < 7; ++c) logits[c] = fmaf(p, wl[k * 7 + c], logits[c]);
    }
    float m = logits[0];
#pragma unroll
    for (int c = 1; c < 7; ++c) m = fmaxf(m, logits[c]);
    float s = 0.f;
#pragma unroll
    for (int c = 0; c < 7; ++c) s += expf(logits[c] - m);
    float lse = m + logf(s);
#pragma unroll
    for (int c = 0; c < 7; ++c) out[g * 7 + c] = logits[c] - lse;
}

extern "C" void kernel_launch(void* const* d_in, const int* in_sizes, int n_in,
                              void* d_out, int out_size, void* d_ws, size_t ws_size,
                              hipStream_t stream) {
    const float* x   = (const float*)d_in[0];
    const float* w1a = (const float*)d_in[1];
    const float* b1a = (const float*)d_in[2];
    const float* w1b = (const float*)d_in[3];
    const float* b1b = (const float*)d_in[4];
    const float* g1  = (const float*)d_in[5];
    const float* be1 = (const float*)d_in[6];
    const float* w2a = (const float*)d_in[7];
    const float* b2a = (const float*)d_in[8];
    const float* w2b = (const float*)d_in[9];
    const float* b2b = (const float*)d_in[10];
    const float* g2  = (const float*)d_in[11];
    const float* be2 = (const float*)d_in[12];
    const float* wl  = (const float*)d_in[13];
    const float* bl  = (const float*)d_in[14];
    const int* ei    = (const int*)d_in[15];
    const int* batch = (const int*)d_in[16];
    float* out = (float*)d_out;

    const int* esrc = ei;
    const int* edst = ei + NE;

    char* ws = (char*)d_ws;
    ushort* B0 = (ushort*)(ws);                   // xb ; later G2
    ushort* B1 = (ushort*)(ws + 25600000);        // G1 ; later H2
    ushort* B2 = (ushort*)(ws + 51200000);        // H1
    int* slots   = (int*)(ws + 76800000);         // NN*64 ints
    int* cursor  = (int*)(ws + 102400000);        // NN ints (degree)
    float* pooled = (float*)(ws + 102800000);     // 256*128 f -> ends 102931072
    float* scale1 = (float*)(ws + 102931072);
    float* shift1 = scale1 + 128;
    float* scale2 = shift1 + 128;
    float* shift2 = scale2 + 128;
    ushort* Wt    = (ushort*)(ws + 102933120);    // 4*16384 bf16 -> ends 103064192
    float4* stat  = (float4*)(ws + 103064192);    // 782*64 float4 = 800768 B
    ushort* Wt1a = Wt, *Wt1b = Wt + 16384, *Wt2a = Wt + 32768, *Wt2b = Wt + 49152;

    const int grid_prep = GRID_FILL + GRID_CAST + GRID_TW;   // 7282
    const int grid_stat = (NN + 255) / 256;                  // 391
    const int grid_gath = (NN + 3) / 4;                      // 25000

    // memset covers cursor + pooled: [102400000, 102931072)
    hipMemsetAsync(cursor, 0, 531072, stream);

    prep<<<grid_prep, 256, 0, stream>>>(esrc, edst, cursor, slots, x, B0, w1a, w1b, w2a, w2b, Wt);

    // ---- layer 1 ----
    gather_slots<0><<<grid_gath, 256, 0, stream>>>(B1, B0, cursor, slots, nullptr, nullptr);   // B1 = x+agg
    gemm_dual<<<GRID_GEMM, 512, 0, stream>>>(B1, Wt1a, b1a, Wt1b, b1b, B2, stat, NN);          // B2 = h1
    bn_finalize<<<1, 64, 0, stream>>>(stat, GRID_GEMM, g1, be1, scale1, shift1, NN);

    // ---- layer 2 (BN1+ReLU fused into gather) ----
    gather_slots<1><<<grid_gath, 256, 0, stream>>>(B0, B2, cursor, slots, scale1, shift1);     // B0 = h1n+agg
    gemm_dual<<<GRID_GEMM, 512, 0, stream>>>(B0, Wt2a, b2a, Wt2b, b2b, B1, stat, NN);          // B1 = h2
    bn_finalize<<<1, 64, 0, stream>>>(stat, GRID_GEMM, g2, be2, scale2, shift2, NN);

    // ---- pool + head ----
    pool_partial<<<grid_stat, 256, 0, stream>>>(B1, batch, scale2, shift2, pooled);
    head<<<1, 256, 0, stream>>>(pooled, batch, wl, bl, out);
}

// Round 11
// 315.896 us; speedup vs baseline: 2.2593x; 2.2593x over previous
//
#include <hip/hip_runtime.h>
#include <math.h>

#define NN 100000
#define NE 1600000
#define NG 256
#define D 128
#define EPS 1e-5f
#define MAXDEG 64
#define EPB 12800
#define SLICE_N 12500
#define GRID_FILL 1000          // (NE/EPB)*8
#define GRID_CAST 6250          // NN*D/8/256
#define GRID_TW 32
#define GRID_GEMM 782           // ceil(NN/128)

typedef __attribute__((ext_vector_type(8))) short s16x8;
typedef __attribute__((ext_vector_type(4))) float f32x4;

__device__ __forceinline__ ushort f2b(float f) {
    uint u = __float_as_uint(f);
    uint r = (u + 0x7fffu + ((u >> 16) & 1u)) >> 16;   // RNE
    return (ushort)r;
}
__device__ __forceinline__ float blo(uint u) { return __uint_as_float(u << 16); }
__device__ __forceinline__ float bhi(uint u) { return __uint_as_float(u & 0xFFFF0000u); }

// W-LDS byte swizzle: XOR row&7 into bits 4-6 of the intra-row offset (involution)
#define SWZW(lin) ((lin) ^ ((((lin) >> 8) & 7) << 4))

// ============ prep: fill (XCD-sliced) + cast x->bf16 + weight transpose, one dispatch ============
__global__ __launch_bounds__(256) void prep(const int* __restrict__ esrc, const int* __restrict__ edst,
                                            int* __restrict__ cursor, int* __restrict__ slots,
                                            const float* __restrict__ x, ushort* __restrict__ xb,
                                            const float* __restrict__ w1a, const float* __restrict__ w1b,
                                            const float* __restrict__ w2a, const float* __restrict__ w2b,
                                            ushort* __restrict__ Wt) {
    int b = blockIdx.x;
    if (b < GRID_FILL) {
        const int slice = b & 7;
        const int chunk = b >> 3;
        const int lo = slice * SLICE_N, hi = lo + SLICE_N;
        const int ebase = chunk * EPB;
        for (int i = threadIdx.x; i < EPB / 4; i += 256) {
            int e = ebase + i * 4;
            int4 s = *(const int4*)(esrc + e);
            int4 d = *(const int4*)(edst + e);
            if (d.x >= lo && d.x < hi) { int p = atomicAdd(&cursor[d.x], 1); slots[(d.x << 6) | (p & 63)] = s.x; }
            if (d.y >= lo && d.y < hi) { int p = atomicAdd(&cursor[d.y], 1); slots[(d.y << 6) | (p & 63)] = s.y; }
            if (d.z >= lo && d.z < hi) { int p = atomicAdd(&cursor[d.z], 1); slots[(d.z << 6) | (p & 63)] = s.z; }
            if (d.w >= lo && d.w < hi) { int p = atomicAdd(&cursor[d.w], 1); slots[(d.w << 6) | (p & 63)] = s.w; }
        }
    } else if (b < GRID_FILL + GRID_CAST) {
        int i = (b - GRID_FILL) * 256 + threadIdx.x;
        if (i * 8 < NN * D) {
            float4 v0 = *(const float4*)(x + i * 8);
            float4 v1 = *(const float4*)(x + i * 8 + 4);
            ushort o[8] = {f2b(v0.x), f2b(v0.y), f2b(v0.z), f2b(v0.w),
                           f2b(v1.x), f2b(v1.y), f2b(v1.z), f2b(v1.w)};
            *(uint4*)(xb + i * 8) = *(uint4*)o;
        }
    } else {
        int by = b - GRID_FILL - GRID_CAST;      // 0..31
        int wsel = by >> 3, bx = by & 7;
        const float* W = (wsel == 0) ? w1a : (wsel == 1) ? w1b : (wsel == 2) ? w2a : w2b;
        ushort* T = Wt + wsel * 16384;
        for (int i = bx * 256 + threadIdx.x; i < 16384; i += 8 * 256) {
            int k = i >> 7, cc = i & 127;
            T[(cc << 7) | k] = f2b(W[i]);
        }
    }
}

// ============ gather, 8 rows in flight, optional fused BN+ReLU ============
template <int FUSE_BN>
__global__ __launch_bounds__(256) void gather_slots(ushort* __restrict__ out, const ushort* __restrict__ feat,
                                                    const int* __restrict__ deg, const int* __restrict__ slots,
                                                    const float* __restrict__ scale, const float* __restrict__ shift) {
    int node = __builtin_amdgcn_readfirstlane(blockIdx.x * 4 + (threadIdx.x >> 6));
    if (node >= NN) return;
    int lane = threadIdx.x & 63;
    int n = deg[node];
    n = (n > MAXDEG) ? MAXDEG : n;
    const int* sl = slots + (node << 6);
    float scx = 1.f, scy = 1.f, shx = 0.f, shy = 0.f;
    if (FUSE_BN) {
        float2 sc = *(const float2*)(scale + lane * 2);
        float2 sh = *(const float2*)(shift + lane * 2);
        scx = sc.x; scy = sc.y; shx = sh.x; shy = sh.y;
    }
    uint ub = *(const uint*)(feat + node * D + lane * 2);
    float axv[8], ayv[8];
#pragma unroll
    for (int j = 0; j < 8; ++j) { axv[j] = 0.f; ayv[j] = 0.f; }
    if (FUSE_BN) {
        axv[0] = fmaxf(fmaf(blo(ub), scx, shx), 0.f);
        ayv[0] = fmaxf(fmaf(bhi(ub), scy, shy), 0.f);
    } else {
        axv[0] = blo(ub); ayv[0] = bhi(ub);
    }
    int e = 0;
    for (; e + 7 < n; e += 8) {
        uint u[8];
#pragma unroll
        for (int j = 0; j < 8; ++j) u[j] = *(const uint*)(feat + sl[e + j] * D + lane * 2);
#pragma unroll
        for (int j = 0; j < 8; ++j) {
            if (FUSE_BN) {
                axv[j] += fmaxf(fmaf(blo(u[j]), scx, shx), 0.f);
                ayv[j] += fmaxf(fmaf(bhi(u[j]), scy, shy), 0.f);
            } else {
                axv[j] += blo(u[j]); ayv[j] += bhi(u[j]);
            }
        }
    }
    for (; e < n; ++e) {
        uint u0 = *(const uint*)(feat + sl[e] * D + lane * 2);
        if (FUSE_BN) {
            axv[0] += fmaxf(fmaf(blo(u0), scx, shx), 0.f);
            ayv[0] += fmaxf(fmaf(bhi(u0), scy, shy), 0.f);
        } else {
            axv[0] += blo(u0); ayv[0] += bhi(u0);
        }
    }
    float ax = ((axv[0] + axv[1]) + (axv[2] + axv[3])) + ((axv[4] + axv[5]) + (axv[6] + axv[7]));
    float ay = ((ayv[0] + ayv[1]) + (ayv[2] + ayv[3])) + ((ayv[4] + ayv[5]) + (ayv[6] + ayv[7]));
    uint o = (uint)f2b(ax) | ((uint)f2b(ay) << 16);
    *(uint*)(out + node * D + lane * 2) = o;
}

// ============ fused dual GEMM + BN partials; W staged in LDS ============
// 512 thr = 8 waves, 128 rows/block, 16 rows/wave. W read via ds_read_b128 (swizzled).
// T/H tile fragment layout: off(row,k) = (k>>5)<<13 | ((k>>3)&3)<<11 | ((row^((k>>3)&7))<<4) | (k&7)<<1
__global__ __launch_bounds__(512, 4) void gemm_dual(const ushort* __restrict__ G,
                                                    const ushort* __restrict__ Wta, const float* __restrict__ ba,
                                                    const ushort* __restrict__ Wtb, const float* __restrict__ bb,
                                                    ushort* __restrict__ H, float4* __restrict__ stat, int nrows) {
    __shared__ ushort wbuf[16384];   // 32 KB swizzled W (Wa then Wb)
    __shared__ ushort tbuf[16384];   // 32 KB T then H, fragment layout
    __shared__ float4 red[8][64];
    char* wb = (char*)wbuf;
    char* tb = (char*)tbuf;

    const int tid = threadIdx.x;
    const int lane = tid & 63;
    const int wave = tid >> 6;          // 0..7
    const int lr = lane & 15;
    const int kg = lane >> 4;
    const int rloc = wave * 16 + lr;    // 0..127
    const int grow = blockIdx.x * 128 + rloc;
    const int growc = (grow > nrows - 1) ? (nrows - 1) : grow;
    const int wrow = lr * 256;          // W row base (row = ct*16+lr; ct*16 ≡ 0 mod 8)
    const int wswz = (lr & 7) << 4;     // XOR mask for bits 4-6 of the intra-row offset

    // ---- prefetch A fragments (coalesced global) ----
    const ushort* gp = G + growc * D + kg * 8;
    s16x8 af0 = *(const s16x8*)(gp);
    s16x8 af1 = *(const s16x8*)(gp + 32);
    s16x8 af2 = *(const s16x8*)(gp + 64);
    s16x8 af3 = *(const s16x8*)(gp + 96);

    // ---- stage Wa -> LDS (swizzled; 512 thr x 64 B) ----
#pragma unroll
    for (int i = 0; i < 4; ++i) {
        int lin = i * 8192 + tid * 16;
        uint4 v = *(const uint4*)((const char*)Wta + lin);
        *(uint4*)(wb + SWZW(lin)) = v;
    }
    __syncthreads();

    f32x4 acc[8];
#pragma unroll
    for (int ct = 0; ct < 8; ++ct) acc[ct] = (f32x4)0.f;

    // ---- stage 1: acc = G @ Wa (W from LDS; full offset XOR) ----
#pragma unroll
    for (int ks = 0; ks < 4; ++ks) {
        s16x8 af = (ks == 0) ? af0 : (ks == 1) ? af1 : (ks == 2) ? af2 : af3;
        const int wofs = (kg * 16 + ks * 64) ^ wswz;
#pragma unroll
        for (int ct = 0; ct < 8; ++ct) {
            s16x8 a = *(const s16x8*)(wb + wrow + ct * 4096 + wofs);
            acc[ct] = __builtin_amdgcn_mfma_f32_16x16x32_bf16(a, af, acc[ct], 0, 0, 0);
        }
    }

    // ---- T = relu(acc + ba) -> tbuf ----
#pragma unroll
    for (int ct = 0; ct < 8; ++ct) {
        int k0 = ct * 16 + kg * 4;
        float4 bv = *(const float4*)(ba + k0);
        float o0 = fmaxf(acc[ct][0] + bv.x, 0.f);
        float o1 = fmaxf(acc[ct][1] + bv.y, 0.f);
        float o2 = fmaxf(acc[ct][2] + bv.z, 0.f);
        float o3 = fmaxf(acc[ct][3] + bv.w, 0.f);
        ushort pk[4] = {f2b(o0), f2b(o1), f2b(o2), f2b(o3)};
        int kb = k0 >> 3;
        int off = ((k0 >> 5) << 13) | ((kb & 3) << 11) | ((rloc ^ (kb & 7)) << 4) | ((k0 & 7) << 1);
        *(uint2*)(tb + off) = *(const uint2*)pk;
    }
    __syncthreads();   // stage-1 W reads + T writes complete

    // ---- stage Wb into wbuf ----
#pragma unroll
    for (int i = 0; i < 4; ++i) {
        int lin = i * 8192 + tid * 16;
        uint4 v = *(const uint4*)((const char*)Wtb + lin);
        *(uint4*)(wb + SWZW(lin)) = v;
    }
    // T fragments (tbuf stable until after next barrier)
    s16x8 bf[4];
#pragma unroll
    for (int ks = 0; ks < 4; ++ks) {
        int kb = ks * 4 + kg;
        bf[ks] = *(const s16x8*)(tb + ((ks << 13) | (kg << 11) | ((rloc ^ (kb & 7)) << 4)));
    }
    __syncthreads();   // Wb staged; all bf reads done

    // ---- stage 2: acc = T @ Wb ----
#pragma unroll
    for (int ct = 0; ct < 8; ++ct) acc[ct] = (f32x4)0.f;
#pragma unroll
    for (int ks = 0; ks < 4; ++ks) {
        const int wofs = (kg * 16 + ks * 64) ^ wswz;
#pragma unroll
        for (int ct = 0; ct < 8; ++ct) {
            s16x8 a = *(const s16x8*)(wb + wrow + ct * 4096 + wofs);
            acc[ct] = __builtin_amdgcn_mfma_f32_16x16x32_bf16(a, bf[ks], acc[ct], 0, 0, 0);
        }
    }

    // ---- H = acc + bb -> global + tbuf (zeros for pad rows) ----
#pragma unroll
    for (int ct = 0; ct < 8; ++ct) {
        int k0 = ct * 16 + kg * 4;
        float4 bv = *(const float4*)(bb + k0);
        uint2 pk2 = make_uint2(0u, 0u);
        if (grow < nrows) {
            float o0 = acc[ct][0] + bv.x;
            float o1 = acc[ct][1] + bv.y;
            float o2 = acc[ct][2] + bv.z;
            float o3 = acc[ct][3] + bv.w;
            ushort pk[4] = {f2b(o0), f2b(o1), f2b(o2), f2b(o3)};
            pk2 = *(const uint2*)pk;
            *(uint2*)(H + grow * D + k0) = pk2;
        }
        int kb = k0 >> 3;
        int off = ((k0 >> 5) << 13) | ((kb & 3) << 11) | ((rloc ^ (kb & 7)) << 4) | ((k0 & 7) << 1);
        *(uint2*)(tb + off) = pk2;
    }
    __syncthreads();

    // ---- column partials over the 128-row tile -> plain stores (no atomics) ----
    {
        int c2 = tid & 63;                      // feature pair 2*c2, 2*c2+1
        int rg = tid >> 6;                      // 0..7 -> 16 rows each
        int k = c2 * 2;
        int kb = k >> 3;
        int base = ((k >> 5) << 13) | ((kb & 3) << 11) | ((k & 7) << 1);
        float s0 = 0.f, q0 = 0.f, s1 = 0.f, q1 = 0.f;
#pragma unroll 4
        for (int i = 0; i < 16; ++i) {
            int row = rg * 16 + i;
            uint u = *(const uint*)(tb + base + ((row ^ (kb & 7)) << 4));
            float lo = blo(u), hi = bhi(u);
            s0 += lo; q0 += lo * lo; s1 += hi; q1 += hi * hi;
        }
        red[rg][c2] = make_float4(s0, q0, s1, q1);
    }
    __syncthreads();
    if (tid < 64) {
        float4 r0 = red[0][tid], r1 = red[1][tid], r2 = red[2][tid], r3 = red[3][tid];
        float4 r4 = red[4][tid], r5 = red[5][tid], r6 = red[6][tid], r7 = red[7][tid];
        float4 o;
        o.x = ((r0.x + r1.x) + (r2.x + r3.x)) + ((r4.x + r5.x) + (r6.x + r7.x));
        o.y = ((r0.y + r1.y) + (r2.y + r3.y)) + ((r4.y + r5.y) + (r6.y + r7.y));
        o.z = ((r0.z + r1.z) + (r2.z + r3.z)) + ((r4.z + r5.z) + (r6.z + r7.z));
        o.w = ((r0.w + r1.w) + (r2.w + r3.w)) + ((r4.w + r5.w) + (r6.w + r7.w));
        stat[blockIdx.x * 64 + tid] = o;
    }
}

// ============ parallel reduce of block partials + finalize scale/shift ============
// 64 blocks (one per float4 column = 2 features) x 256 threads
__global__ __launch_bounds__(256) void bn_reduce(const float4* __restrict__ stat, int nblk,
                                                 const float* __restrict__ gamma, const float* __restrict__ beta,
                                                 float* __restrict__ scale, float* __restrict__ shift, int nrows) {
    const int f4 = blockIdx.x;      // 0..63
    const int t = threadIdx.x;
    float s0 = 0.f, q0 = 0.f, s1 = 0.f, q1 = 0.f;
    for (int b = t; b < nblk; b += 256) {
        float4 v = stat[b * 64 + f4];
        s0 += v.x; q0 += v.y; s1 += v.z; q1 += v.w;
    }
    __shared__ float4 red[256];
    red[t] = make_float4(s0, q0, s1, q1);
    __syncthreads();
    for (int off = 128; off >= 1; off >>= 1) {
        if (t < off) {
            float4 a = red[t], b = red[t + off];
            red[t] = make_float4(a.x + b.x, a.y + b.y, a.z + b.z, a.w + b.w);
        }
        __syncthreads();
    }
    if (t == 0) {
        float4 v = red[0];
        int f0 = 2 * f4, f1 = 2 * f4 + 1;
        double m0 = (double)v.x / nrows, var0 = (double)v.y / nrows - m0 * m0;
        double m1 = (double)v.z / nrows, var1 = (double)v.w / nrows - m1 * m1;
        float sc0 = gamma[f0] * rsqrtf((float)var0 + EPS);
        float sc1 = gamma[f1] * rsqrtf((float)var1 + EPS);
        scale[f0] = sc0; shift[f0] = beta[f0] - (float)m0 * sc0;
        scale[f1] = sc1; shift[f1] = beta[f1] - (float)m1 * sc1;
    }
}

// ============ pool: partial sums into pooled[g][f] via run-flush atomics ============
__global__ __launch_bounds__(256) void pool_partial(const ushort* __restrict__ h, const int* __restrict__ batch,
                                                    const float* __restrict__ scale, const float* __restrict__ shift,
                                                    float* __restrict__ pooled) {
    int wave = threadIdx.x >> 6;
    int lane = threadIdx.x & 63;
    int r0 = blockIdx.x * 256 + wave * 64;
    if (r0 >= NN) return;
    int f2 = lane * 2;
    float2 sc = *(const float2*)(scale + f2);
    float2 sh = *(const float2*)(shift + f2);
    float ax = 0.f, ay = 0.f;
    int cur = -1;
    int rend = r0 + 64; if (rend > NN) rend = NN;
    for (int r = r0; r < rend; ++r) {
        int g = batch[r];
        if (g != cur) {
            if (cur >= 0) {
                atomicAdd(&pooled[cur * D + f2], ax);
                atomicAdd(&pooled[cur * D + f2 + 1], ay);
            }
            cur = g; ax = 0.f; ay = 0.f;
        }
        uint u = *(const uint*)(h + r * D + f2);
        ax += fmaxf(fmaf(blo(u), sc.x, sh.x), 0.f);
        ay += fmaxf(fmaf(bhi(u), sc.y, sh.y), 0.f);
    }
    if (cur >= 0) {
        atomicAdd(&pooled[cur * D + f2], ax);
        atomicAdd(&pooled[cur * D + f2 + 1], ay);
    }
}

__device__ __forceinline__ int lower_bound_i(const int* a, int n, int v) {
    int lo = 0, hi = n;
    while (lo < hi) {
        int m = (lo + hi) >> 1;
        if (a[m] < v) lo = m + 1; else hi = m;
    }
    return lo;
}

__global__ __launch_bounds__(256) void head(const float* __restrict__ pooled, const int* __restrict__ batch,
                                            const float* __restrict__ wl, const float* __restrict__ bl,
                                            float* __restrict__ out) {
    int g = blockIdx.x * 256 + threadIdx.x;
    if (g >= NG) return;
    int lo = lower_bound_i(batch, NN, g);
    int hi = lower_bound_i(batch, NN, g + 1);
    float inv = 1.f / fmaxf((float)(hi - lo), 1.f);
    float logits[7];
#pragma unroll
    for (int c = 0; c < 7; ++c) logits[c] = bl[c];
    for (int k = 0; k < D; ++k) {
        float p = pooled[g * D + k] * inv;
#pragma unroll
        for (int c = 0; c < 7; ++c) logits[c] = fmaf(p, wl[k * 7 + c], logits[c]);
    }
    float m = logits[0];
#pragma unroll
    for (int c = 1; c < 7; ++c) m = fmaxf(m, logits[c]);
    float s = 0.f;
#pragma unroll
    for (int c = 0; c < 7; ++c) s += expf(logits[c] - m);
    float lse = m + logf(s);
#pragma unroll
    for (int c = 0; c < 7; ++c) out[g * 7 + c] = logits[c] - lse;
}

extern "C" void kernel_launch(void* const* d_in, const int* in_sizes, int n_in,
                              void* d_out, int out_size, void* d_ws, size_t ws_size,
                              hipStream_t stream) {
    const float* x   = (const float*)d_in[0];
    const float* w1a = (const float*)d_in[1];
    const float* b1a = (const float*)d_in[2];
    const float* w1b = (const float*)d_in[3];
    const float* b1b = (const float*)d_in[4];
    const float* g1  = (const float*)d_in[5];
    const float* be1 = (const float*)d_in[6];
    const float* w2a = (const float*)d_in[7];
    const float* b2a = (const float*)d_in[8];
    const float* w2b = (const float*)d_in[9];
    const float* b2b = (const float*)d_in[10];
    const float* g2  = (const float*)d_in[11];
    const float* be2 = (const float*)d_in[12];
    const float* wl  = (const float*)d_in[13];
    const float* bl  = (const float*)d_in[14];
    const int* ei    = (const int*)d_in[15];
    const int* batch = (const int*)d_in[16];
    float* out = (float*)d_out;

    const int* esrc = ei;
    const int* edst = ei + NE;

    char* ws = (char*)d_ws;
    ushort* B0 = (ushort*)(ws);                   // xb ; later G2
    ushort* B1 = (ushort*)(ws + 25600000);        // G1 ; later H2
    ushort* B2 = (ushort*)(ws + 51200000);        // H1
    int* slots   = (int*)(ws + 76800000);         // NN*64 ints
    int* cursor  = (int*)(ws + 102400000);        // NN ints (degree)
    float* pooled = (float*)(ws + 102800000);     // 256*128 f -> ends 102931072
    float* scale1 = (float*)(ws + 102931072);
    float* shift1 = scale1 + 128;
    float* scale2 = shift1 + 128;
    float* shift2 = scale2 + 128;
    ushort* Wt    = (ushort*)(ws + 102933120);    // 4*16384 bf16 -> ends 103064192
    float4* stat  = (float4*)(ws + 103064192);    // 782*64 float4 = 800768 B
    ushort* Wt1a = Wt, *Wt1b = Wt + 16384, *Wt2a = Wt + 32768, *Wt2b = Wt + 49152;

    const int grid_prep = GRID_FILL + GRID_CAST + GRID_TW;   // 7282
    const int grid_stat = (NN + 255) / 256;                  // 391
    const int grid_gath = (NN + 3) / 4;                      // 25000

    // memset covers cursor + pooled: [102400000, 102931072)
    hipMemsetAsync(cursor, 0, 531072, stream);

    prep<<<grid_prep, 256, 0, stream>>>(esrc, edst, cursor, slots, x, B0, w1a, w1b, w2a, w2b, Wt);

    // ---- layer 1 ----
    gather_slots<0><<<grid_gath, 256, 0, stream>>>(B1, B0, cursor, slots, nullptr, nullptr);   // B1 = x+agg
    gemm_dual<<<GRID_GEMM, 512, 0, stream>>>(B1, Wt1a, b1a, Wt1b, b1b, B2, stat, NN);          // B2 = h1
    bn_reduce<<<64, 256, 0, stream>>>(stat, GRID_GEMM, g1, be1, scale1, shift1, NN);

    // ---- layer 2 (BN1+ReLU fused into gather) ----
    gather_slots<1><<<grid_gath, 256, 0, stream>>>(B0, B2, cursor, slots, scale1, shift1);     // B0 = h1n+agg
    gemm_dual<<<GRID_GEMM, 512, 0, stream>>>(B0, Wt2a, b2a, Wt2b, b2b, B1, stat, NN);          // B1 = h2
    bn_reduce<<<64, 256, 0, stream>>>(stat, GRID_GEMM, g2, be2, scale2, shift2, NN);

    // ---- pool + head ----
    pool_partial<<<grid_stat, 256, 0, stream>>>(B1, batch, scale2, shift2, pooled);
    head<<<1, 256, 0, stream>>>(pooled, batch, wl, bl, out);
}

// Round 13
// 310.639 us; speedup vs baseline: 2.2975x; 1.0169x over previous
//
#include <hip/hip_runtime.h>
#include <math.h>

#define NN 100000
#define NE 1600000
#define NG 256
#define D 128
#define EPS 1e-5f
#define MAXDEG 64
#define EPB 12800
#define SLICE_N 12500
#define GRID_FILL 1000          // (NE/EPB)*8
#define GRID_CAST 6250          // NN*D/8/256
#define GRID_TW 32
#define GRID_GEMM 782           // ceil(NN/128)

typedef __attribute__((ext_vector_type(8))) short s16x8;
typedef __attribute__((ext_vector_type(4))) float f32x4;
typedef __attribute__((ext_vector_type(4))) float f32x4v;   // for nontemporal builtins
typedef __attribute__((ext_vector_type(4))) uint u32x4;

__device__ __forceinline__ ushort f2b(float f) {
    uint u = __float_as_uint(f);
    uint r = (u + 0x7fffu + ((u >> 16) & 1u)) >> 16;   // RNE
    return (ushort)r;
}
__device__ __forceinline__ float blo(uint u) { return __uint_as_float(u << 16); }
__device__ __forceinline__ float bhi(uint u) { return __uint_as_float(u & 0xFFFF0000u); }

// W-LDS byte swizzle: XOR row&7 into bits 4-6 of the intra-row offset (involution)
#define SWZW(lin) ((lin) ^ ((((lin) >> 8) & 7) << 4))

// ============ prep: fill (XCD-sliced) + cast x->bf16 (non-temporal) + weight transpose ============
__global__ __launch_bounds__(256) void prep(const int* __restrict__ esrc, const int* __restrict__ edst,
                                            int* __restrict__ cursor, int* __restrict__ slots,
                                            const float* __restrict__ x, ushort* __restrict__ xb,
                                            const float* __restrict__ w1a, const float* __restrict__ w1b,
                                            const float* __restrict__ w2a, const float* __restrict__ w2b,
                                            ushort* __restrict__ Wt) {
    int b = blockIdx.x;
    if (b < GRID_FILL) {
        const int slice = b & 7;
        const int chunk = b >> 3;
        const int lo = slice * SLICE_N, hi = lo + SLICE_N;
        const int ebase = chunk * EPB;
        for (int i = threadIdx.x; i < EPB / 4; i += 256) {
            int e = ebase + i * 4;
            int4 s = *(const int4*)(esrc + e);
            int4 d = *(const int4*)(edst + e);
            if (d.x >= lo && d.x < hi) { int p = atomicAdd(&cursor[d.x], 1); slots[(d.x << 6) | (p & 63)] = s.x; }
            if (d.y >= lo && d.y < hi) { int p = atomicAdd(&cursor[d.y], 1); slots[(d.y << 6) | (p & 63)] = s.y; }
            if (d.z >= lo && d.z < hi) { int p = atomicAdd(&cursor[d.z], 1); slots[(d.z << 6) | (p & 63)] = s.z; }
            if (d.w >= lo && d.w < hi) { int p = atomicAdd(&cursor[d.w], 1); slots[(d.w << 6) | (p & 63)] = s.w; }
        }
    } else if (b < GRID_FILL + GRID_CAST) {
        int i = (b - GRID_FILL) * 256 + threadIdx.x;
        if (i * 8 < NN * D) {
            // non-temporal: don't evict fill's dirty slot lines from L2
            f32x4v v0 = __builtin_nontemporal_load((const f32x4v*)(x + i * 8));
            f32x4v v1 = __builtin_nontemporal_load((const f32x4v*)(x + i * 8) + 1);
            ushort o[8] = {f2b(v0.x), f2b(v0.y), f2b(v0.z), f2b(v0.w),
                           f2b(v1.x), f2b(v1.y), f2b(v1.z), f2b(v1.w)};
            __builtin_nontemporal_store(*(u32x4*)o, (u32x4*)(xb + i * 8));
        }
    } else {
        int by = b - GRID_FILL - GRID_CAST;      // 0..31
        int wsel = by >> 3, bx = by & 7;
        const float* W = (wsel == 0) ? w1a : (wsel == 1) ? w1b : (wsel == 2) ? w2a : w2b;
        ushort* T = Wt + wsel * 16384;
        for (int i = bx * 256 + threadIdx.x; i < 16384; i += 8 * 256) {
            int k = i >> 7, cc = i & 127;
            T[(cc << 7) | k] = f2b(W[i]);
        }
    }
}

// ============ gather, 16 rows in flight, optional fused BN+ReLU ============
template <int FUSE_BN>
__global__ __launch_bounds__(256) void gather_slots(ushort* __restrict__ out, const ushort* __restrict__ feat,
                                                    const int* __restrict__ deg, const int* __restrict__ slots,
                                                    const float* __restrict__ scale, const float* __restrict__ shift) {
    int node = __builtin_amdgcn_readfirstlane(blockIdx.x * 4 + (threadIdx.x >> 6));
    if (node >= NN) return;
    int lane = threadIdx.x & 63;
    int n = deg[node];
    n = (n > MAXDEG) ? MAXDEG : n;
    const int* sl = slots + (node << 6);
    float scx = 1.f, scy = 1.f, shx = 0.f, shy = 0.f;
    if (FUSE_BN) {
        float2 sc = *(const float2*)(scale + lane * 2);
        float2 sh = *(const float2*)(shift + lane * 2);
        scx = sc.x; scy = sc.y; shx = sh.x; shy = sh.y;
    }
    uint ub = *(const uint*)(feat + node * D + lane * 2);
    float axv[8], ayv[8];
#pragma unroll
    for (int j = 0; j < 8; ++j) { axv[j] = 0.f; ayv[j] = 0.f; }
    if (FUSE_BN) {
        axv[0] = fmaxf(fmaf(blo(ub), scx, shx), 0.f);
        ayv[0] = fmaxf(fmaf(bhi(ub), scy, shy), 0.f);
    } else {
        axv[0] = blo(ub); ayv[0] = bhi(ub);
    }
    int e = 0;
    // 16 independent loads in flight (mean degree = 16); wave-uniform trip counts
    for (; e + 15 < n; e += 16) {
        uint u[16];
#pragma unroll
        for (int j = 0; j < 16; ++j) u[j] = *(const uint*)(feat + sl[e + j] * D + lane * 2);
#pragma unroll
        for (int j = 0; j < 16; ++j) {
            int j8 = j & 7;
            if (FUSE_BN) {
                axv[j8] += fmaxf(fmaf(blo(u[j]), scx, shx), 0.f);
                ayv[j8] += fmaxf(fmaf(bhi(u[j]), scy, shy), 0.f);
            } else {
                axv[j8] += blo(u[j]); ayv[j8] += bhi(u[j]);
            }
        }
    }
    for (; e + 7 < n; e += 8) {
        uint u[8];
#pragma unroll
        for (int j = 0; j < 8; ++j) u[j] = *(const uint*)(feat + sl[e + j] * D + lane * 2);
#pragma unroll
        for (int j = 0; j < 8; ++j) {
            if (FUSE_BN) {
                axv[j] += fmaxf(fmaf(blo(u[j]), scx, shx), 0.f);
                ayv[j] += fmaxf(fmaf(bhi(u[j]), scy, shy), 0.f);
            } else {
                axv[j] += blo(u[j]); ayv[j] += bhi(u[j]);
            }
        }
    }
    for (; e + 3 < n; e += 4) {
        uint u[4];
#pragma unroll
        for (int j = 0; j < 4; ++j) u[j] = *(const uint*)(feat + sl[e + j] * D + lane * 2);
#pragma unroll
        for (int j = 0; j < 4; ++j) {
            if (FUSE_BN) {
                axv[j] += fmaxf(fmaf(blo(u[j]), scx, shx), 0.f);
                ayv[j] += fmaxf(fmaf(bhi(u[j]), scy, shy), 0.f);
            } else {
                axv[j] += blo(u[j]); ayv[j] += bhi(u[j]);
            }
        }
    }
    for (; e < n; ++e) {
        uint u0 = *(const uint*)(feat + sl[e] * D + lane * 2);
        if (FUSE_BN) {
            axv[0] += fmaxf(fmaf(blo(u0), scx, shx), 0.f);
            ayv[0] += fmaxf(fmaf(bhi(u0), scy, shy), 0.f);
        } else {
            axv[0] += blo(u0); ayv[0] += bhi(u0);
        }
    }
    float ax = ((axv[0] + axv[1]) + (axv[2] + axv[3])) + ((axv[4] + axv[5]) + (axv[6] + axv[7]));
    float ay = ((ayv[0] + ayv[1]) + (ayv[2] + ayv[3])) + ((ayv[4] + ayv[5]) + (ayv[6] + ayv[7]));
    uint o = (uint)f2b(ax) | ((uint)f2b(ay) << 16);
    *(uint*)(out + node * D + lane * 2) = o;
}

// ============ fused dual GEMM + BN partials; W staged in LDS ============
__global__ __launch_bounds__(512, 4) void gemm_dual(const ushort* __restrict__ G,
                                                    const ushort* __restrict__ Wta, const float* __restrict__ ba,
                                                    const ushort* __restrict__ Wtb, const float* __restrict__ bb,
                                                    ushort* __restrict__ H, float4* __restrict__ stat, int nrows) {
    __shared__ ushort wbuf[16384];   // 32 KB swizzled W (Wa then Wb)
    __shared__ ushort tbuf[16384];   // 32 KB T then H, fragment layout
    __shared__ float4 red[8][64];
    char* wb = (char*)wbuf;
    char* tb = (char*)tbuf;

    const int tid = threadIdx.x;
    const int lane = tid & 63;
    const int wave = tid >> 6;          // 0..7
    const int lr = lane & 15;
    const int kg = lane >> 4;
    const int rloc = wave * 16 + lr;    // 0..127
    const int grow = blockIdx.x * 128 + rloc;
    const int growc = (grow > nrows - 1) ? (nrows - 1) : grow;
    const int wrow = lr * 256;
    const int wswz = (lr & 7) << 4;

    // ---- prefetch A fragments (coalesced global) ----
    const ushort* gp = G + growc * D + kg * 8;
    s16x8 af0 = *(const s16x8*)(gp);
    s16x8 af1 = *(const s16x8*)(gp + 32);
    s16x8 af2 = *(const s16x8*)(gp + 64);
    s16x8 af3 = *(const s16x8*)(gp + 96);

    // ---- stage Wa -> LDS (swizzled) ----
#pragma unroll
    for (int i = 0; i < 4; ++i) {
        int lin = i * 8192 + tid * 16;
        uint4 v = *(const uint4*)((const char*)Wta + lin);
        *(uint4*)(wb + SWZW(lin)) = v;
    }
    __syncthreads();

    f32x4 acc[8];
#pragma unroll
    for (int ct = 0; ct < 8; ++ct) acc[ct] = (f32x4)0.f;

    // ---- stage 1: acc = G @ Wa ----
#pragma unroll
    for (int ks = 0; ks < 4; ++ks) {
        s16x8 af = (ks == 0) ? af0 : (ks == 1) ? af1 : (ks == 2) ? af2 : af3;
        const int wofs = (kg * 16 + ks * 64) ^ wswz;
#pragma unroll
        for (int ct = 0; ct < 8; ++ct) {
            s16x8 a = *(const s16x8*)(wb + wrow + ct * 4096 + wofs);
            acc[ct] = __builtin_amdgcn_mfma_f32_16x16x32_bf16(a, af, acc[ct], 0, 0, 0);
        }
    }

    // ---- T = relu(acc + ba) -> tbuf ----
#pragma unroll
    for (int ct = 0; ct < 8; ++ct) {
        int k0 = ct * 16 + kg * 4;
        float4 bv = *(const float4*)(ba + k0);
        float o0 = fmaxf(acc[ct][0] + bv.x, 0.f);
        float o1 = fmaxf(acc[ct][1] + bv.y, 0.f);
        float o2 = fmaxf(acc[ct][2] + bv.z, 0.f);
        float o3 = fmaxf(acc[ct][3] + bv.w, 0.f);
        ushort pk[4] = {f2b(o0), f2b(o1), f2b(o2), f2b(o3)};
        int kb = k0 >> 3;
        int off = ((k0 >> 5) << 13) | ((kb & 3) << 11) | ((rloc ^ (kb & 7)) << 4) | ((k0 & 7) << 1);
        *(uint2*)(tb + off) = *(const uint2*)pk;
    }
    __syncthreads();

    // ---- stage Wb into wbuf ----
#pragma unroll
    for (int i = 0; i < 4; ++i) {
        int lin = i * 8192 + tid * 16;
        uint4 v = *(const uint4*)((const char*)Wtb + lin);
        *(uint4*)(wb + SWZW(lin)) = v;
    }
    // T fragments
    s16x8 bf[4];
#pragma unroll
    for (int ks = 0; ks < 4; ++ks) {
        int kb = ks * 4 + kg;
        bf[ks] = *(const s16x8*)(tb + ((ks << 13) | (kg << 11) | ((rloc ^ (kb & 7)) << 4)));
    }
    __syncthreads();

    // ---- stage 2: acc = T @ Wb ----
#pragma unroll
    for (int ct = 0; ct < 8; ++ct) acc[ct] = (f32x4)0.f;
#pragma unroll
    for (int ks = 0; ks < 4; ++ks) {
        const int wofs = (kg * 16 + ks * 64) ^ wswz;
#pragma unroll
        for (int ct = 0; ct < 8; ++ct) {
            s16x8 a = *(const s16x8*)(wb + wrow + ct * 4096 + wofs);
            acc[ct] = __builtin_amdgcn_mfma_f32_16x16x32_bf16(a, bf[ks], acc[ct], 0, 0, 0);
        }
    }

    // ---- H = acc + bb -> global + tbuf ----
#pragma unroll
    for (int ct = 0; ct < 8; ++ct) {
        int k0 = ct * 16 + kg * 4;
        float4 bv = *(const float4*)(bb + k0);
        uint2 pk2 = make_uint2(0u, 0u);
        if (grow < nrows) {
            float o0 = acc[ct][0] + bv.x;
            float o1 = acc[ct][1] + bv.y;
            float o2 = acc[ct][2] + bv.z;
            float o3 = acc[ct][3] + bv.w;
            ushort pk[4] = {f2b(o0), f2b(o1), f2b(o2), f2b(o3)};
            pk2 = *(const uint2*)pk;
            *(uint2*)(H + grow * D + k0) = pk2;
        }
        int kb = k0 >> 3;
        int off = ((k0 >> 5) << 13) | ((kb & 3) << 11) | ((rloc ^ (kb & 7)) << 4) | ((k0 & 7) << 1);
        *(uint2*)(tb + off) = pk2;
    }
    __syncthreads();

    // ---- column partials -> plain stores ----
    {
        int c2 = tid & 63;
        int rg = tid >> 6;
        int k = c2 * 2;
        int kb = k >> 3;
        int base = ((k >> 5) << 13) | ((kb & 3) << 11) | ((k & 7) << 1);
        float s0 = 0.f, q0 = 0.f, s1 = 0.f, q1 = 0.f;
#pragma unroll 4
        for (int i = 0; i < 16; ++i) {
            int row = rg * 16 + i;
            uint u = *(const uint*)(tb + base + ((row ^ (kb & 7)) << 4));
            float lo = blo(u), hi = bhi(u);
            s0 += lo; q0 += lo * lo; s1 += hi; q1 += hi * hi;
        }
        red[rg][c2] = make_float4(s0, q0, s1, q1);
    }
    __syncthreads();
    if (tid < 64) {
        float4 r0 = red[0][tid], r1 = red[1][tid], r2 = red[2][tid], r3 = red[3][tid];
        float4 r4 = red[4][tid], r5 = red[5][tid], r6 = red[6][tid], r7 = red[7][tid];
        float4 o;
        o.x = ((r0.x + r1.x) + (r2.x + r3.x)) + ((r4.x + r5.x) + (r6.x + r7.x));
        o.y = ((r0.y + r1.y) + (r2.y + r3.y)) + ((r4.y + r5.y) + (r6.y + r7.y));
        o.z = ((r0.z + r1.z) + (r2.z + r3.z)) + ((r4.z + r5.z) + (r6.z + r7.z));
        o.w = ((r0.w + r1.w) + (r2.w + r3.w)) + ((r4.w + r5.w) + (r6.w + r7.w));
        stat[blockIdx.x * 64 + tid] = o;
    }
}

// ============ parallel reduce of block partials + finalize scale/shift ============
__global__ __launch_bounds__(256) void bn_reduce(const float4* __restrict__ stat, int nblk,
                                                 const float* __restrict__ gamma, const float* __restrict__ beta,
                                                 float* __restrict__ scale, float* __restrict__ shift, int nrows) {
    const int f4 = blockIdx.x;      // 0..63
    const int t = threadIdx.x;
    float s0 = 0.f, q0 = 0.f, s1 = 0.f, q1 = 0.f;
    for (int b = t; b < nblk; b += 256) {
        float4 v = stat[b * 64 + f4];
        s0 += v.x; q0 += v.y; s1 += v.z; q1 += v.w;
    }
    __shared__ float4 red[256];
    red[t] = make_float4(s0, q0, s1, q1);
    __syncthreads();
    for (int off = 128; off >= 1; off >>= 1) {
        if (t < off) {
            float4 a = red[t], b = red[t + off];
            red[t] = make_float4(a.x + b.x, a.y + b.y, a.z + b.z, a.w + b.w);
        }
        __syncthreads();
    }
    if (t == 0) {
        float4 v = red[0];
        int f0 = 2 * f4, f1 = 2 * f4 + 1;
        double m0 = (double)v.x / nrows, var0 = (double)v.y / nrows - m0 * m0;
        double m1 = (double)v.z / nrows, var1 = (double)v.w / nrows - m1 * m1;
        float sc0 = gamma[f0] * rsqrtf((float)var0 + EPS);
        float sc1 = gamma[f1] * rsqrtf((float)var1 + EPS);
        scale[f0] = sc0; shift[f0] = beta[f0] - (float)m0 * sc0;
        scale[f1] = sc1; shift[f1] = beta[f1] - (float)m1 * sc1;
    }
}

// ============ pool: partial sums into pooled[g][f] via run-flush atomics ============
__global__ __launch_bounds__(256) void pool_partial(const ushort* __restrict__ h, const int* __restrict__ batch,
                                                    const float* __restrict__ scale, const float* __restrict__ shift,
                                                    float* __restrict__ pooled) {
    int wave = threadIdx.x >> 6;
    int lane = threadIdx.x & 63;
    int r0 = blockIdx.x * 256 + wave * 64;
    if (r0 >= NN) return;
    int f2 = lane * 2;
    float2 sc = *(const float2*)(scale + f2);
    float2 sh = *(const float2*)(shift + f2);
    float ax = 0.f, ay = 0.f;
    int cur = -1;
    int rend = r0 + 64; if (rend > NN) rend = NN;
    for (int r = r0; r < rend; ++r) {
        int g = batch[r];
        if (g != cur) {
            if (cur >= 0) {
                atomicAdd(&pooled[cur * D + f2], ax);
                atomicAdd(&pooled[cur * D + f2 + 1], ay);
            }
            cur = g; ax = 0.f; ay = 0.f;
        }
        uint u = *(const uint*)(h + r * D + f2);
        ax += fmaxf(fmaf(blo(u), sc.x, sh.x), 0.f);
        ay += fmaxf(fmaf(bhi(u), sc.y, sh.y), 0.f);
    }
    if (cur >= 0) {
        atomicAdd(&pooled[cur * D + f2], ax);
        atomicAdd(&pooled[cur * D + f2 + 1], ay);
    }
}

__device__ __forceinline__ int lower_bound_i(const int* a, int n, int v) {
    int lo = 0, hi = n;
    while (lo < hi) {
        int m = (lo + hi) >> 1;
        if (a[m] < v) lo = m + 1; else hi = m;
    }
    return lo;
}

__global__ __launch_bounds__(256) void head(const float* __restrict__ pooled, const int* __restrict__ batch,
                                            const float* __restrict__ wl, const float* __restrict__ bl,
                                            float* __restrict__ out) {
    int g = blockIdx.x * 256 + threadIdx.x;
    if (g >= NG) return;
    int lo = lower_bound_i(batch, NN, g);
    int hi = lower_bound_i(batch, NN, g + 1);
    float inv = 1.f / fmaxf((float)(hi - lo), 1.f);
    float logits[7];
#pragma unroll
    for (int c = 0; c < 7; ++c) logits[c] = bl[c];
    for (int k = 0; k < D; ++k) {
        float p = pooled[g * D + k] * inv;
#pragma unroll
        for (int c = 0; c < 7; ++c) logits[c] = fmaf(p, wl[k * 7 + c], logits[c]);
    }
    float m = logits[0];
#pragma unroll
    for (int c = 1; c < 7; ++c) m = fmaxf(m, logits[c]);
    float s = 0.f;
#pragma unroll
    for (int c = 0; c < 7; ++c) s += expf(logits[c] - m);
    float lse = m + logf(s);
#pragma unroll
    for (int c = 0; c < 7; ++c) out[g * 7 + c] = logits[c] - lse;
}

extern "C" void kernel_launch(void* const* d_in, const int* in_sizes, int n_in,
                              void* d_out, int out_size, void* d_ws, size_t ws_size,
                              hipStream_t stream) {
    const float* x   = (const float*)d_in[0];
    const float* w1a = (const float*)d_in[1];
    const float* b1a = (const float*)d_in[2];
    const float* w1b = (const float*)d_in[3];
    const float* b1b = (const float*)d_in[4];
    const float* g1  = (const float*)d_in[5];
    const float* be1 = (const float*)d_in[6];
    const float* w2a = (const float*)d_in[7];
    const float* b2a = (const float*)d_in[8];
    const float* w2b = (const float*)d_in[9];
    const float* b2b = (const float*)d_in[10];
    const float* g2  = (const float*)d_in[11];
    const float* be2 = (const float*)d_in[12];
    const float* wl  = (const float*)d_in[13];
    const float* bl  = (const float*)d_in[14];
    const int* ei    = (const int*)d_in[15];
    const int* batch = (const int*)d_in[16];
    float* out = (float*)d_out;

    const int* esrc = ei;
    const int* edst = ei + NE;

    char* ws = (char*)d_ws;
    ushort* B0 = (ushort*)(ws);                   // xb ; later G2
    ushort* B1 = (ushort*)(ws + 25600000);        // G1 ; later H2
    ushort* B2 = (ushort*)(ws + 51200000);        // H1
    int* slots   = (int*)(ws + 76800000);         // NN*64 ints
    int* cursor  = (int*)(ws + 102400000);        // NN ints (degree)
    float* pooled = (float*)(ws + 102800000);     // 256*128 f -> ends 102931072
    float* scale1 = (float*)(ws + 102931072);
    float* shift1 = scale1 + 128;
    float* scale2 = shift1 + 128;
    float* shift2 = scale2 + 128;
    ushort* Wt    = (ushort*)(ws + 102933120);    // 4*16384 bf16 -> ends 103064192
    float4* stat  = (float4*)(ws + 103064192);    // 782*64 float4
    ushort* Wt1a = Wt, *Wt1b = Wt + 16384, *Wt2a = Wt + 32768, *Wt2b = Wt + 49152;

    const int grid_prep = GRID_FILL + GRID_CAST + GRID_TW;   // 7282
    const int grid_stat = (NN + 255) / 256;                  // 391
    const int grid_gath = (NN + 3) / 4;                      // 25000

    // memset covers cursor + pooled: [102400000, 102931072)
    hipMemsetAsync(cursor, 0, 531072, stream);

    prep<<<grid_prep, 256, 0, stream>>>(esrc, edst, cursor, slots, x, B0, w1a, w1b, w2a, w2b, Wt);

    // ---- layer 1 ----
    gather_slots<0><<<grid_gath, 256, 0, stream>>>(B1, B0, cursor, slots, nullptr, nullptr);   // B1 = x+agg
    gemm_dual<<<GRID_GEMM, 512, 0, stream>>>(B1, Wt1a, b1a, Wt1b, b1b, B2, stat, NN);          // B2 = h1
    bn_reduce<<<64, 256, 0, stream>>>(stat, GRID_GEMM, g1, be1, scale1, shift1, NN);

    // ---- layer 2 (BN1+ReLU fused into gather) ----
    gather_slots<1><<<grid_gath, 256, 0, stream>>>(B0, B2, cursor, slots, scale1, shift1);     // B0 = h1n+agg
    gemm_dual<<<GRID_GEMM, 512, 0, stream>>>(B0, Wt2a, b2a, Wt2b, b2b, B1, stat, NN);          // B1 = h2
    bn_reduce<<<64, 256, 0, stream>>>(stat, GRID_GEMM, g2, be2, scale2, shift2, NN);

    // ---- pool + head ----
    pool_partial<<<grid_stat, 256, 0, stream>>>(B1, batch, scale2, shift2, pooled);
    head<<<1, 256, 0, stream>>>(pooled, batch, wl, bl, out);
}

// Round 14
// 289.954 us; speedup vs baseline: 2.4614x; 1.0713x over previous
//
#include <hip/hip_runtime.h>
#include <math.h>

#define NN 100000
#define NE 1600000
#define NG 256
#define D 128
#define EPS 1e-5f
#define MAXDEG 64
#define NBINS 196           // ceil(NN/512)
#define BINSZ 512
#define BINCAP 12288        // mean 8163, sd ~90 -> +45 sigma
#define GRID_BIN 125
#define EPB_A 12800         // NE / 125
#define GRID_CAST 6250      // NN*D/8/256
#define GRID_TW 32
#define GRID_GEMM 782       // ceil(NN/128)

typedef __attribute__((ext_vector_type(8))) short s16x8;
typedef __attribute__((ext_vector_type(4))) float f32x4;

__device__ __forceinline__ ushort f2b(float f) {
    uint u = __float_as_uint(f);
    uint r = (u + 0x7fffu + ((u >> 16) & 1u)) >> 16;   // RNE
    return (ushort)r;
}
__device__ __forceinline__ float blo(uint u) { return __uint_as_float(u << 16); }
__device__ __forceinline__ float bhi(uint u) { return __uint_as_float(u & 0xFFFF0000u); }

// W-LDS byte swizzle: XOR row&7 into bits 4-6 of the intra-row offset (involution)
#define SWZW(lin) ((lin) ^ ((((lin) >> 8) & 7) << 4))

// ============ prep1: bin edges (packed u32) + cast x->bf16 + weight transpose ============
__global__ __launch_bounds__(256) void prep1(const int* __restrict__ esrc, const int* __restrict__ edst,
                                             uint* __restrict__ binbuf, int* __restrict__ bincnt,
                                             const float* __restrict__ x, ushort* __restrict__ xb,
                                             const float* __restrict__ w1a, const float* __restrict__ w1b,
                                             const float* __restrict__ w2a, const float* __restrict__ w2b,
                                             ushort* __restrict__ Wt) {
    int b = blockIdx.x;
    if (b < GRID_BIN) {
        __shared__ int cnt[NBINS], lbase[NBINS];
        const int ebase = b * EPB_A;
        for (int it = 0; it < 13; ++it) {
            for (int t = threadIdx.x; t < NBINS; t += 256) cnt[t] = 0;
            __syncthreads();
            int e = ebase + it * 1024 + threadIdx.x * 4;
            bool valid = (e < ebase + EPB_A);
            int4 s = make_int4(0, 0, 0, 0), d = make_int4(0, 0, 0, 0);
            if (valid) {
                s = *(const int4*)(esrc + e);
                d = *(const int4*)(edst + e);
            }
            int b0 = d.x >> 9, b1 = d.y >> 9, b2 = d.z >> 9, b3 = d.w >> 9;
            int o0 = 0, o1 = 0, o2 = 0, o3 = 0;
            if (valid) {
                o0 = atomicAdd(&cnt[b0], 1);
                o1 = atomicAdd(&cnt[b1], 1);
                o2 = atomicAdd(&cnt[b2], 1);
                o3 = atomicAdd(&cnt[b3], 1);
            }
            __syncthreads();
            for (int t = threadIdx.x; t < NBINS; t += 256)
                lbase[t] = (cnt[t] > 0) ? atomicAdd(&bincnt[t], cnt[t]) : 0;
            __syncthreads();
            if (valid) {
                uint p0 = (uint)(lbase[b0] + o0), p1 = (uint)(lbase[b1] + o1);
                uint p2 = (uint)(lbase[b2] + o2), p3 = (uint)(lbase[b3] + o3);
                if (p0 < BINCAP) binbuf[b0 * BINCAP + p0] = ((uint)(d.x & 511) << 17) | (uint)s.x;
                if (p1 < BINCAP) binbuf[b1 * BINCAP + p1] = ((uint)(d.y & 511) << 17) | (uint)s.y;
                if (p2 < BINCAP) binbuf[b2 * BINCAP + p2] = ((uint)(d.z & 511) << 17) | (uint)s.z;
                if (p3 < BINCAP) binbuf[b3 * BINCAP + p3] = ((uint)(d.w & 511) << 17) | (uint)s.w;
            }
        }
    } else if (b < GRID_BIN + GRID_CAST) {
        int i = (b - GRID_BIN) * 256 + threadIdx.x;
        if (i * 8 < NN * D) {
            float4 v0 = *(const float4*)(x + i * 8);
            float4 v1 = *(const float4*)(x + i * 8 + 4);
            ushort o[8] = {f2b(v0.x), f2b(v0.y), f2b(v0.z), f2b(v0.w),
                           f2b(v1.x), f2b(v1.y), f2b(v1.z), f2b(v1.w)};
            *(uint4*)(xb + i * 8) = *(uint4*)o;
        }
    } else {
        int by = b - GRID_BIN - GRID_CAST;       // 0..31
        int wsel = by >> 3, bx = by & 7;
        const float* W = (wsel == 0) ? w1a : (wsel == 1) ? w1b : (wsel == 2) ? w2a : w2b;
        ushort* T = Wt + wsel * 16384;
        for (int i = bx * 256 + threadIdx.x; i < 16384; i += 8 * 256) {
            int k = i >> 7, cc = i & 127;
            T[(cc << 7) | k] = f2b(W[i]);
        }
    }
}

// ============ drain: one block per bin; LDS counters (no global atomics); writes slots + deg ============
__global__ __launch_bounds__(256) void drain(const uint* __restrict__ binbuf, const int* __restrict__ bincnt,
                                             int* __restrict__ deg, int* __restrict__ slots) {
    const int bin = blockIdx.x;
    int n = bincnt[bin]; if (n > BINCAP) n = BINCAP;
    __shared__ int cur[BINSZ];
    cur[threadIdx.x] = 0;
    cur[threadIdx.x + 256] = 0;
    __syncthreads();
    const uint* bp = binbuf + bin * BINCAP;
    const int base = bin << 9;
    int i = threadIdx.x;
    for (; i + 768 < n; i += 1024) {
        uint u0 = bp[i], u1 = bp[i + 256], u2 = bp[i + 512], u3 = bp[i + 768];
        int l0 = u0 >> 17, l1 = u1 >> 17, l2 = u2 >> 17, l3 = u3 >> 17;
        int p0 = atomicAdd(&cur[l0], 1);
        int p1 = atomicAdd(&cur[l1], 1);
        int p2 = atomicAdd(&cur[l2], 1);
        int p3 = atomicAdd(&cur[l3], 1);
        slots[((base + l0) << 6) | (p0 & 63)] = (int)(u0 & 0x1FFFFu);
        slots[((base + l1) << 6) | (p1 & 63)] = (int)(u1 & 0x1FFFFu);
        slots[((base + l2) << 6) | (p2 & 63)] = (int)(u2 & 0x1FFFFu);
        slots[((base + l3) << 6) | (p3 & 63)] = (int)(u3 & 0x1FFFFu);
    }
    for (; i < n; i += 256) {
        uint u0 = bp[i];
        int l0 = u0 >> 17;
        int p0 = atomicAdd(&cur[l0], 1);
        slots[((base + l0) << 6) | (p0 & 63)] = (int)(u0 & 0x1FFFFu);
    }
    __syncthreads();
    int node = base + threadIdx.x;
    if (node < NN) deg[node] = cur[threadIdx.x];
    node += 256;
    if (node < NN) deg[node] = cur[threadIdx.x + 256];
}

// ============ gather, 16 rows in flight, optional fused BN+ReLU ============
template <int FUSE_BN>
__global__ __launch_bounds__(256) void gather_slots(ushort* __restrict__ out, const ushort* __restrict__ feat,
                                                    const int* __restrict__ deg, const int* __restrict__ slots,
                                                    const float* __restrict__ scale, const float* __restrict__ shift) {
    int node = __builtin_amdgcn_readfirstlane(blockIdx.x * 4 + (threadIdx.x >> 6));
    if (node >= NN) return;
    int lane = threadIdx.x & 63;
    int n = deg[node];
    n = (n > MAXDEG) ? MAXDEG : n;
    const int* sl = slots + (node << 6);
    float scx = 1.f, scy = 1.f, shx = 0.f, shy = 0.f;
    if (FUSE_BN) {
        float2 sc = *(const float2*)(scale + lane * 2);
        float2 sh = *(const float2*)(shift + lane * 2);
        scx = sc.x; scy = sc.y; shx = sh.x; shy = sh.y;
    }
    uint ub = *(const uint*)(feat + node * D + lane * 2);
    float axv[8], ayv[8];
#pragma unroll
    for (int j = 0; j < 8; ++j) { axv[j] = 0.f; ayv[j] = 0.f; }
    if (FUSE_BN) {
        axv[0] = fmaxf(fmaf(blo(ub), scx, shx), 0.f);
        ayv[0] = fmaxf(fmaf(bhi(ub), scy, shy), 0.f);
    } else {
        axv[0] = blo(ub); ayv[0] = bhi(ub);
    }
    int e = 0;
    for (; e + 15 < n; e += 16) {
        uint u[16];
#pragma unroll
        for (int j = 0; j < 16; ++j) u[j] = *(const uint*)(feat + sl[e + j] * D + lane * 2);
#pragma unroll
        for (int j = 0; j < 16; ++j) {
            int j8 = j & 7;
            if (FUSE_BN) {
                axv[j8] += fmaxf(fmaf(blo(u[j]), scx, shx), 0.f);
                ayv[j8] += fmaxf(fmaf(bhi(u[j]), scy, shy), 0.f);
            } else {
                axv[j8] += blo(u[j]); ayv[j8] += bhi(u[j]);
            }
        }
    }
    for (; e + 7 < n; e += 8) {
        uint u[8];
#pragma unroll
        for (int j = 0; j < 8; ++j) u[j] = *(const uint*)(feat + sl[e + j] * D + lane * 2);
#pragma unroll
        for (int j = 0; j < 8; ++j) {
            if (FUSE_BN) {
                axv[j] += fmaxf(fmaf(blo(u[j]), scx, shx), 0.f);
                ayv[j] += fmaxf(fmaf(bhi(u[j]), scy, shy), 0.f);
            } else {
                axv[j] += blo(u[j]); ayv[j] += bhi(u[j]);
            }
        }
    }
    for (; e + 3 < n; e += 4) {
        uint u[4];
#pragma unroll
        for (int j = 0; j < 4; ++j) u[j] = *(const uint*)(feat + sl[e + j] * D + lane * 2);
#pragma unroll
        for (int j = 0; j < 4; ++j) {
            if (FUSE_BN) {
                axv[j] += fmaxf(fmaf(blo(u[j]), scx, shx), 0.f);
                ayv[j] += fmaxf(fmaf(bhi(u[j]), scy, shy), 0.f);
            } else {
                axv[j] += blo(u[j]); ayv[j] += bhi(u[j]);
            }
        }
    }
    for (; e < n; ++e) {
        uint u0 = *(const uint*)(feat + sl[e] * D + lane * 2);
        if (FUSE_BN) {
            axv[0] += fmaxf(fmaf(blo(u0), scx, shx), 0.f);
            ayv[0] += fmaxf(fmaf(bhi(u0), scy, shy), 0.f);
        } else {
            axv[0] += blo(u0); ayv[0] += bhi(u0);
        }
    }
    float ax = ((axv[0] + axv[1]) + (axv[2] + axv[3])) + ((axv[4] + axv[5]) + (axv[6] + axv[7]));
    float ay = ((ayv[0] + ayv[1]) + (ayv[2] + ayv[3])) + ((ayv[4] + ayv[5]) + (ayv[6] + ayv[7]));
    uint o = (uint)f2b(ax) | ((uint)f2b(ay) << 16);
    *(uint*)(out + node * D + lane * 2) = o;
}

// ============ fused dual GEMM + BN partials; W staged in LDS ============
__global__ __launch_bounds__(512, 4) void gemm_dual(const ushort* __restrict__ G,
                                                    const ushort* __restrict__ Wta, const float* __restrict__ ba,
                                                    const ushort* __restrict__ Wtb, const float* __restrict__ bb,
                                                    ushort* __restrict__ H, float4* __restrict__ stat, int nrows) {
    __shared__ ushort wbuf[16384];   // 32 KB swizzled W (Wa then Wb)
    __shared__ ushort tbuf[16384];   // 32 KB T then H, fragment layout
    __shared__ float4 red[8][64];
    char* wb = (char*)wbuf;
    char* tb = (char*)tbuf;

    const int tid = threadIdx.x;
    const int lane = tid & 63;
    const int wave = tid >> 6;          // 0..7
    const int lr = lane & 15;
    const int kg = lane >> 4;
    const int rloc = wave * 16 + lr;    // 0..127
    const int grow = blockIdx.x * 128 + rloc;
    const int growc = (grow > nrows - 1) ? (nrows - 1) : grow;
    const int wrow = lr * 256;
    const int wswz = (lr & 7) << 4;

    // ---- prefetch A fragments (coalesced global) ----
    const ushort* gp = G + growc * D + kg * 8;
    s16x8 af0 = *(const s16x8*)(gp);
    s16x8 af1 = *(const s16x8*)(gp + 32);
    s16x8 af2 = *(const s16x8*)(gp + 64);
    s16x8 af3 = *(const s16x8*)(gp + 96);

    // ---- stage Wa -> LDS (swizzled) ----
#pragma unroll
    for (int i = 0; i < 4; ++i) {
        int lin = i * 8192 + tid * 16;
        uint4 v = *(const uint4*)((const char*)Wta + lin);
        *(uint4*)(wb + SWZW(lin)) = v;
    }
    __syncthreads();

    f32x4 acc[8];
#pragma unroll
    for (int ct = 0; ct < 8; ++ct) acc[ct] = (f32x4)0.f;

    // ---- stage 1: acc = G @ Wa ----
#pragma unroll
    for (int ks = 0; ks < 4; ++ks) {
        s16x8 af = (ks == 0) ? af0 : (ks == 1) ? af1 : (ks == 2) ? af2 : af3;
        const int wofs = (kg * 16 + ks * 64) ^ wswz;
#pragma unroll
        for (int ct = 0; ct < 8; ++ct) {
            s16x8 a = *(const s16x8*)(wb + wrow + ct * 4096 + wofs);
            acc[ct] = __builtin_amdgcn_mfma_f32_16x16x32_bf16(a, af, acc[ct], 0, 0, 0);
        }
    }

    // ---- T = relu(acc + ba) -> tbuf ----
#pragma unroll
    for (int ct = 0; ct < 8; ++ct) {
        int k0 = ct * 16 + kg * 4;
        float4 bv = *(const float4*)(ba + k0);
        float o0 = fmaxf(acc[ct][0] + bv.x, 0.f);
        float o1 = fmaxf(acc[ct][1] + bv.y, 0.f);
        float o2 = fmaxf(acc[ct][2] + bv.z, 0.f);
        float o3 = fmaxf(acc[ct][3] + bv.w, 0.f);
        ushort pk[4] = {f2b(o0), f2b(o1), f2b(o2), f2b(o3)};
        int kb = k0 >> 3;
        int off = ((k0 >> 5) << 13) | ((kb & 3) << 11) | ((rloc ^ (kb & 7)) << 4) | ((k0 & 7) << 1);
        *(uint2*)(tb + off) = *(const uint2*)pk;
    }
    __syncthreads();

    // ---- stage Wb into wbuf ----
#pragma unroll
    for (int i = 0; i < 4; ++i) {
        int lin = i * 8192 + tid * 16;
        uint4 v = *(const uint4*)((const char*)Wtb + lin);
        *(uint4*)(wb + SWZW(lin)) = v;
    }
    // T fragments
    s16x8 bf[4];
#pragma unroll
    for (int ks = 0; ks < 4; ++ks) {
        int kb = ks * 4 + kg;
        bf[ks] = *(const s16x8*)(tb + ((ks << 13) | (kg << 11) | ((rloc ^ (kb & 7)) << 4)));
    }
    __syncthreads();

    // ---- stage 2: acc = T @ Wb ----
#pragma unroll
    for (int ct = 0; ct < 8; ++ct) acc[ct] = (f32x4)0.f;
#pragma unroll
    for (int ks = 0; ks < 4; ++ks) {
        const int wofs = (kg * 16 + ks * 64) ^ wswz;
#pragma unroll
        for (int ct = 0; ct < 8; ++ct) {
            s16x8 a = *(const s16x8*)(wb + wrow + ct * 4096 + wofs);
            acc[ct] = __builtin_amdgcn_mfma_f32_16x16x32_bf16(a, bf[ks], acc[ct], 0, 0, 0);
        }
    }

    // ---- H = acc + bb -> global + tbuf ----
#pragma unroll
    for (int ct = 0; ct < 8; ++ct) {
        int k0 = ct * 16 + kg * 4;
        float4 bv = *(const float4*)(bb + k0);
        uint2 pk2 = make_uint2(0u, 0u);
        if (grow < nrows) {
            float o0 = acc[ct][0] + bv.x;
            float o1 = acc[ct][1] + bv.y;
            float o2 = acc[ct][2] + bv.z;
            float o3 = acc[ct][3] + bv.w;
            ushort pk[4] = {f2b(o0), f2b(o1), f2b(o2), f2b(o3)};
            pk2 = *(const uint2*)pk;
            *(uint2*)(H + grow * D + k0) = pk2;
        }
        int kb = k0 >> 3;
        int off = ((k0 >> 5) << 13) | ((kb & 3) << 11) | ((rloc ^ (kb & 7)) << 4) | ((k0 & 7) << 1);
        *(uint2*)(tb + off) = pk2;
    }
    __syncthreads();

    // ---- column partials -> plain stores ----
    {
        int c2 = tid & 63;
        int rg = tid >> 6;
        int k = c2 * 2;
        int kb = k >> 3;
        int base = ((k >> 5) << 13) | ((kb & 3) << 11) | ((k & 7) << 1);
        float s0 = 0.f, q0 = 0.f, s1 = 0.f, q1 = 0.f;
#pragma unroll 4
        for (int i = 0; i < 16; ++i) {
            int row = rg * 16 + i;
            uint u = *(const uint*)(tb + base + ((row ^ (kb & 7)) << 4));
            float lo = blo(u), hi = bhi(u);
            s0 += lo; q0 += lo * lo; s1 += hi; q1 += hi * hi;
        }
        red[rg][c2] = make_float4(s0, q0, s1, q1);
    }
    __syncthreads();
    if (tid < 64) {
        float4 r0 = red[0][tid], r1 = red[1][tid], r2 = red[2][tid], r3 = red[3][tid];
        float4 r4 = red[4][tid], r5 = red[5][tid], r6 = red[6][tid], r7 = red[7][tid];
        float4 o;
        o.x = ((r0.x + r1.x) + (r2.x + r3.x)) + ((r4.x + r5.x) + (r6.x + r7.x));
        o.y = ((r0.y + r1.y) + (r2.y + r3.y)) + ((r4.y + r5.y) + (r6.y + r7.y));
        o.z = ((r0.z + r1.z) + (r2.z + r3.z)) + ((r4.z + r5.z) + (r6.z + r7.z));
        o.w = ((r0.w + r1.w) + (r2.w + r3.w)) + ((r4.w + r5.w) + (r6.w + r7.w));
        stat[blockIdx.x * 64 + tid] = o;
    }
}

// ============ parallel reduce of block partials + finalize scale/shift ============
__global__ __launch_bounds__(256) void bn_reduce(const float4* __restrict__ stat, int nblk,
                                                 const float* __restrict__ gamma, const float* __restrict__ beta,
                                                 float* __restrict__ scale, float* __restrict__ shift, int nrows) {
    const int f4 = blockIdx.x;      // 0..63
    const int t = threadIdx.x;
    float s0 = 0.f, q0 = 0.f, s1 = 0.f, q1 = 0.f;
    for (int b = t; b < nblk; b += 256) {
        float4 v = stat[b * 64 + f4];
        s0 += v.x; q0 += v.y; s1 += v.z; q1 += v.w;
    }
    __shared__ float4 red[256];
    red[t] = make_float4(s0, q0, s1, q1);
    __syncthreads();
    for (int off = 128; off >= 1; off >>= 1) {
        if (t < off) {
            float4 a = red[t], b = red[t + off];
            red[t] = make_float4(a.x + b.x, a.y + b.y, a.z + b.z, a.w + b.w);
        }
        __syncthreads();
    }
    if (t == 0) {
        float4 v = red[0];
        int f0 = 2 * f4, f1 = 2 * f4 + 1;
        double m0 = (double)v.x / nrows, var0 = (double)v.y / nrows - m0 * m0;
        double m1 = (double)v.z / nrows, var1 = (double)v.w / nrows - m1 * m1;
        float sc0 = gamma[f0] * rsqrtf((float)var0 + EPS);
        float sc1 = gamma[f1] * rsqrtf((float)var1 + EPS);
        scale[f0] = sc0; shift[f0] = beta[f0] - (float)m0 * sc0;
        scale[f1] = sc1; shift[f1] = beta[f1] - (float)m1 * sc1;
    }
}

// ============ pool: partial sums into pooled[g][f] via run-flush atomics ============
__global__ __launch_bounds__(256) void pool_partial(const ushort* __restrict__ h, const int* __restrict__ batch,
                                                    const float* __restrict__ scale, const float* __restrict__ shift,
                                                    float* __restrict__ pooled) {
    int wave = threadIdx.x >> 6;
    int lane = threadIdx.x & 63;
    int r0 = blockIdx.x * 256 + wave * 64;
    if (r0 >= NN) return;
    int f2 = lane * 2;
    float2 sc = *(const float2*)(scale + f2);
    float2 sh = *(const float2*)(shift + f2);
    float ax = 0.f, ay = 0.f;
    int cur = -1;
    int rend = r0 + 64; if (rend > NN) rend = NN;
    for (int r = r0; r < rend; ++r) {
        int g = batch[r];
        if (g != cur) {
            if (cur >= 0) {
                atomicAdd(&pooled[cur * D + f2], ax);
                atomicAdd(&pooled[cur * D + f2 + 1], ay);
            }
            cur = g; ax = 0.f; ay = 0.f;
        }
        uint u = *(const uint*)(h + r * D + f2);
        ax += fmaxf(fmaf(blo(u), sc.x, sh.x), 0.f);
        ay += fmaxf(fmaf(bhi(u), sc.y, sh.y), 0.f);
    }
    if (cur >= 0) {
        atomicAdd(&pooled[cur * D + f2], ax);
        atomicAdd(&pooled[cur * D + f2 + 1], ay);
    }
}

__device__ __forceinline__ int lower_bound_i(const int* a, int n, int v) {
    int lo = 0, hi = n;
    while (lo < hi) {
        int m = (lo + hi) >> 1;
        if (a[m] < v) lo = m + 1; else hi = m;
    }
    return lo;
}

__global__ __launch_bounds__(256) void head(const float* __restrict__ pooled, const int* __restrict__ batch,
                                            const float* __restrict__ wl, const float* __restrict__ bl,
                                            float* __restrict__ out) {
    int g = blockIdx.x * 256 + threadIdx.x;
    if (g >= NG) return;
    int lo = lower_bound_i(batch, NN, g);
    int hi = lower_bound_i(batch, NN, g + 1);
    float inv = 1.f / fmaxf((float)(hi - lo), 1.f);
    float logits[7];
#pragma unroll
    for (int c = 0; c < 7; ++c) logits[c] = bl[c];
    for (int k = 0; k < D; ++k) {
        float p = pooled[g * D + k] * inv;
#pragma unroll
        for (int c = 0; c < 7; ++c) logits[c] = fmaf(p, wl[k * 7 + c], logits[c]);
    }
    float m = logits[0];
#pragma unroll
    for (int c = 1; c < 7; ++c) m = fmaxf(m, logits[c]);
    float s = 0.f;
#pragma unroll
    for (int c = 0; c < 7; ++c) s += expf(logits[c] - m);
    float lse = m + logf(s);
#pragma unroll
    for (int c = 0; c < 7; ++c) out[g * 7 + c] = logits[c] - lse;
}

extern "C" void kernel_launch(void* const* d_in, const int* in_sizes, int n_in,
                              void* d_out, int out_size, void* d_ws, size_t ws_size,
                              hipStream_t stream) {
    const float* x   = (const float*)d_in[0];
    const float* w1a = (const float*)d_in[1];
    const float* b1a = (const float*)d_in[2];
    const float* w1b = (const float*)d_in[3];
    const float* b1b = (const float*)d_in[4];
    const float* g1  = (const float*)d_in[5];
    const float* be1 = (const float*)d_in[6];
    const float* w2a = (const float*)d_in[7];
    const float* b2a = (const float*)d_in[8];
    const float* w2b = (const float*)d_in[9];
    const float* b2b = (const float*)d_in[10];
    const float* g2  = (const float*)d_in[11];
    const float* be2 = (const float*)d_in[12];
    const float* wl  = (const float*)d_in[13];
    const float* bl  = (const float*)d_in[14];
    const int* ei    = (const int*)d_in[15];
    const int* batch = (const int*)d_in[16];
    float* out = (float*)d_out;

    const int* esrc = ei;
    const int* edst = ei + NE;

    char* ws = (char*)d_ws;
    ushort* B0 = (ushort*)(ws);                   // xb ; later G2
    ushort* B1 = (ushort*)(ws + 25600000);        // binbuf during build; then G1 / H2
    ushort* B2 = (ushort*)(ws + 51200000);        // H1
    uint* binbuf = (uint*)(ws + 25600000);        // 196*12288*4 = 9.6 MB (dead before gather1)
    int* slots   = (int*)(ws + 76800000);         // NN*64 ints
    int* deg     = (int*)(ws + 102400000);        // NN ints (written by drain, no memset)
    int* bincnt  = (int*)(ws + 102800000);        // 196 ints (memset)
    float* pooled = (float*)(ws + 102801024);     // 131072 B (memset) -> ends 102932096
    float* scale1 = (float*)(ws + 102932096);
    float* shift1 = scale1 + 128;
    float* scale2 = shift1 + 128;
    float* shift2 = scale2 + 128;
    ushort* Wt    = (ushort*)(ws + 102934144);    // 131072 B -> ends 103065216
    float4* stat  = (float4*)(ws + 103065216);    // 782*64 float4
    ushort* Wt1a = Wt, *Wt1b = Wt + 16384, *Wt2a = Wt + 32768, *Wt2b = Wt + 49152;

    const int grid_prep = GRID_BIN + GRID_CAST + GRID_TW;    // 6407
    const int grid_stat = (NN + 255) / 256;                  // 391
    const int grid_gath = (NN + 3) / 4;                      // 25000

    // memset covers bincnt + pooled: [102800000, 102932096)
    hipMemsetAsync(bincnt, 0, 132096, stream);

    prep1<<<grid_prep, 256, 0, stream>>>(esrc, edst, binbuf, bincnt, x, B0, w1a, w1b, w2a, w2b, Wt);
    drain<<<NBINS, 256, 0, stream>>>(binbuf, bincnt, deg, slots);

    // ---- layer 1 ----
    gather_slots<0><<<grid_gath, 256, 0, stream>>>(B1, B0, deg, slots, nullptr, nullptr);      // B1 = x+agg
    gemm_dual<<<GRID_GEMM, 512, 0, stream>>>(B1, Wt1a, b1a, Wt1b, b1b, B2, stat, NN);          // B2 = h1
    bn_reduce<<<64, 256, 0, stream>>>(stat, GRID_GEMM, g1, be1, scale1, shift1, NN);

    // ---- layer 2 (BN1+ReLU fused into gather) ----
    gather_slots<1><<<grid_gath, 256, 0, stream>>>(B0, B2, deg, slots, scale1, shift1);        // B0 = h1n+agg
    gemm_dual<<<GRID_GEMM, 512, 0, stream>>>(B0, Wt2a, b2a, Wt2b, b2b, B1, stat, NN);          // B1 = h2
    bn_reduce<<<64, 256, 0, stream>>>(stat, GRID_GEMM, g2, be2, scale2, shift2, NN);

    // ---- pool + head ----
    pool_partial<<<grid_stat, 256, 0, stream>>>(B1, batch, scale2, shift2, pooled);
    head<<<1, 256, 0, stream>>>(pooled, batch, wl, bl, out);
}

// Round 15
// 288.457 us; speedup vs baseline: 2.4742x; 1.0052x over previous
//
#include <hip/hip_runtime.h>
#include <math.h>

#define NN 100000
#define NE 1600000
#define NG 256
#define D 128
#define EPS 1e-5f
#define MAXDEG 64
#define NBINS 196           // ceil(NN/512)
#define BINSZ 512
#define BINCAP 12288
#define GRID_BIN 250
#define EPB_A 6400          // NE / 250
#define GRID_CAST 6250      // NN*D/8/256
#define GRID_TW 32
#define GRID_GEMM 782       // ceil(NN/128)

typedef __attribute__((ext_vector_type(8))) short s16x8;
typedef __attribute__((ext_vector_type(4))) float f32x4;
typedef __attribute__((ext_vector_type(2))) float f32x2;

__device__ __forceinline__ ushort f2b(float f) {
    uint u = __float_as_uint(f);
    uint r = (u + 0x7fffu + ((u >> 16) & 1u)) >> 16;   // RNE
    return (ushort)r;
}
__device__ __forceinline__ float blo(uint u) { return __uint_as_float(u << 16); }
__device__ __forceinline__ float bhi(uint u) { return __uint_as_float(u & 0xFFFF0000u); }
__device__ __forceinline__ f32x2 unpk2(uint u) {
    f32x2 v; v.x = blo(u); v.y = bhi(u); return v;
}

// W-LDS byte swizzle: XOR row&7 into bits 4-6 of the intra-row offset (involution)
#define SWZW(lin) ((lin) ^ ((((lin) >> 8) & 7) << 4))

// ============ prep1: bin edges (packed u32) + cast x->bf16 + weight transpose ============
__global__ __launch_bounds__(256) void prep1(const int* __restrict__ esrc, const int* __restrict__ edst,
                                             uint* __restrict__ binbuf, int* __restrict__ bincnt,
                                             const float* __restrict__ x, ushort* __restrict__ xb,
                                             const float* __restrict__ w1a, const float* __restrict__ w1b,
                                             const float* __restrict__ w2a, const float* __restrict__ w2b,
                                             ushort* __restrict__ Wt) {
    int b = blockIdx.x;
    if (b < GRID_BIN) {
        __shared__ int cnt[NBINS], lbase[NBINS];
        const int ebase = b * EPB_A;
        for (int it = 0; it < 7; ++it) {
            for (int t = threadIdx.x; t < NBINS; t += 256) cnt[t] = 0;
            __syncthreads();
            int e = ebase + it * 1024 + threadIdx.x * 4;
            bool valid = (e < ebase + EPB_A);
            int4 s = make_int4(0, 0, 0, 0), d = make_int4(0, 0, 0, 0);
            if (valid) {
                s = *(const int4*)(esrc + e);
                d = *(const int4*)(edst + e);
            }
            int b0 = d.x >> 9, b1 = d.y >> 9, b2 = d.z >> 9, b3 = d.w >> 9;
            int o0 = 0, o1 = 0, o2 = 0, o3 = 0;
            if (valid) {
                o0 = atomicAdd(&cnt[b0], 1);
                o1 = atomicAdd(&cnt[b1], 1);
                o2 = atomicAdd(&cnt[b2], 1);
                o3 = atomicAdd(&cnt[b3], 1);
            }
            __syncthreads();
            for (int t = threadIdx.x; t < NBINS; t += 256)
                lbase[t] = (cnt[t] > 0) ? atomicAdd(&bincnt[t], cnt[t]) : 0;
            __syncthreads();
            if (valid) {
                uint p0 = (uint)(lbase[b0] + o0), p1 = (uint)(lbase[b1] + o1);
                uint p2 = (uint)(lbase[b2] + o2), p3 = (uint)(lbase[b3] + o3);
                if (p0 < BINCAP) binbuf[b0 * BINCAP + p0] = ((uint)(d.x & 511) << 17) | (uint)s.x;
                if (p1 < BINCAP) binbuf[b1 * BINCAP + p1] = ((uint)(d.y & 511) << 17) | (uint)s.y;
                if (p2 < BINCAP) binbuf[b2 * BINCAP + p2] = ((uint)(d.z & 511) << 17) | (uint)s.z;
                if (p3 < BINCAP) binbuf[b3 * BINCAP + p3] = ((uint)(d.w & 511) << 17) | (uint)s.w;
            }
        }
    } else if (b < GRID_BIN + GRID_CAST) {
        int i = (b - GRID_BIN) * 256 + threadIdx.x;
        if (i * 8 < NN * D) {
            float4 v0 = *(const float4*)(x + i * 8);
            float4 v1 = *(const float4*)(x + i * 8 + 4);
            ushort o[8] = {f2b(v0.x), f2b(v0.y), f2b(v0.z), f2b(v0.w),
                           f2b(v1.x), f2b(v1.y), f2b(v1.z), f2b(v1.w)};
            *(uint4*)(xb + i * 8) = *(uint4*)o;
        }
    } else {
        int by = b - GRID_BIN - GRID_CAST;       // 0..31
        int wsel = by >> 3, bx = by & 7;
        const float* W = (wsel == 0) ? w1a : (wsel == 1) ? w1b : (wsel == 2) ? w2a : w2b;
        ushort* T = Wt + wsel * 16384;
        for (int i = bx * 256 + threadIdx.x; i < 16384; i += 8 * 256) {
            int k = i >> 7, cc = i & 127;
            T[(cc << 7) | k] = f2b(W[i]);
        }
    }
}

// ============ drain: one block per bin; LDS counters; writes slots + deg ============
__global__ __launch_bounds__(256) void drain(const uint* __restrict__ binbuf, const int* __restrict__ bincnt,
                                             int* __restrict__ deg, int* __restrict__ slots) {
    const int bin = blockIdx.x;
    int n = bincnt[bin]; if (n > BINCAP) n = BINCAP;
    __shared__ int cur[BINSZ];
    cur[threadIdx.x] = 0;
    cur[threadIdx.x + 256] = 0;
    __syncthreads();
    const uint* bp = binbuf + bin * BINCAP;
    const int base = bin << 9;
    int i = threadIdx.x;
    for (; i + 768 < n; i += 1024) {
        uint u0 = bp[i], u1 = bp[i + 256], u2 = bp[i + 512], u3 = bp[i + 768];
        int l0 = u0 >> 17, l1 = u1 >> 17, l2 = u2 >> 17, l3 = u3 >> 17;
        int p0 = atomicAdd(&cur[l0], 1);
        int p1 = atomicAdd(&cur[l1], 1);
        int p2 = atomicAdd(&cur[l2], 1);
        int p3 = atomicAdd(&cur[l3], 1);
        slots[((base + l0) << 6) | (p0 & 63)] = (int)(u0 & 0x1FFFFu);
        slots[((base + l1) << 6) | (p1 & 63)] = (int)(u1 & 0x1FFFFu);
        slots[((base + l2) << 6) | (p2 & 63)] = (int)(u2 & 0x1FFFFu);
        slots[((base + l3) << 6) | (p3 & 63)] = (int)(u3 & 0x1FFFFu);
    }
    for (; i < n; i += 256) {
        uint u0 = bp[i];
        int l0 = u0 >> 17;
        int p0 = atomicAdd(&cur[l0], 1);
        slots[((base + l0) << 6) | (p0 & 63)] = (int)(u0 & 0x1FFFFu);
    }
    __syncthreads();
    int node = base + threadIdx.x;
    if (node < NN) deg[node] = cur[threadIdx.x];
    node += 256;
    if (node < NN) deg[node] = cur[threadIdx.x + 256];
}

// ============ gather, 16 rows in flight, packed-f32 math, optional fused BN+ReLU ============
template <int FUSE_BN>
__global__ __launch_bounds__(256) void gather_slots(ushort* __restrict__ out, const ushort* __restrict__ feat,
                                                    const int* __restrict__ deg, const int* __restrict__ slots,
                                                    const float* __restrict__ scale, const float* __restrict__ shift) {
    int node = __builtin_amdgcn_readfirstlane(blockIdx.x * 4 + (threadIdx.x >> 6));
    if (node >= NN) return;
    int lane = threadIdx.x & 63;
    int n = deg[node];
    n = (n > MAXDEG) ? MAXDEG : n;
    const int* sl = slots + (node << 6);
    f32x2 sc2 = (f32x2)1.f, sh2 = (f32x2)0.f;
    if (FUSE_BN) {
        float2 sc = *(const float2*)(scale + lane * 2);
        float2 sh = *(const float2*)(shift + lane * 2);
        sc2.x = sc.x; sc2.y = sc.y; sh2.x = sh.x; sh2.y = sh.y;
    }
    uint ub = *(const uint*)(feat + node * D + lane * 2);
    f32x2 acc[8];
#pragma unroll
    for (int j = 0; j < 8; ++j) acc[j] = (f32x2)0.f;
    {
        f32x2 v = unpk2(ub);
        if (FUSE_BN) {
            f32x2 t = v * sc2 + sh2;                         // v_pk_fma_f32
            acc[0] = __builtin_elementwise_max(t, (f32x2)0.f);  // v_pk_max_f32
        } else {
            acc[0] = v;
        }
    }
    int e = 0;
    for (; e + 15 < n; e += 16) {
        uint u[16];
#pragma unroll
        for (int j = 0; j < 16; ++j) u[j] = *(const uint*)(feat + sl[e + j] * D + lane * 2);
#pragma unroll
        for (int j = 0; j < 16; ++j) {
            f32x2 v = unpk2(u[j]);
            if (FUSE_BN) {
                f32x2 t = v * sc2 + sh2;
                acc[j & 7] += __builtin_elementwise_max(t, (f32x2)0.f);
            } else {
                acc[j & 7] += v;                              // v_pk_add_f32
            }
        }
    }
    for (; e + 7 < n; e += 8) {
        uint u[8];
#pragma unroll
        for (int j = 0; j < 8; ++j) u[j] = *(const uint*)(feat + sl[e + j] * D + lane * 2);
#pragma unroll
        for (int j = 0; j < 8; ++j) {
            f32x2 v = unpk2(u[j]);
            if (FUSE_BN) {
                f32x2 t = v * sc2 + sh2;
                acc[j] += __builtin_elementwise_max(t, (f32x2)0.f);
            } else {
                acc[j] += v;
            }
        }
    }
    for (; e + 3 < n; e += 4) {
        uint u[4];
#pragma unroll
        for (int j = 0; j < 4; ++j) u[j] = *(const uint*)(feat + sl[e + j] * D + lane * 2);
#pragma unroll
        for (int j = 0; j < 4; ++j) {
            f32x2 v = unpk2(u[j]);
            if (FUSE_BN) {
                f32x2 t = v * sc2 + sh2;
                acc[j] += __builtin_elementwise_max(t, (f32x2)0.f);
            } else {
                acc[j] += v;
            }
        }
    }
    for (; e < n; ++e) {
        f32x2 v = unpk2(*(const uint*)(feat + sl[e] * D + lane * 2));
        if (FUSE_BN) {
            f32x2 t = v * sc2 + sh2;
            acc[0] += __builtin_elementwise_max(t, (f32x2)0.f);
        } else {
            acc[0] += v;
        }
    }
    f32x2 s = ((acc[0] + acc[1]) + (acc[2] + acc[3])) + ((acc[4] + acc[5]) + (acc[6] + acc[7]));
    uint o = (uint)f2b(s.x) | ((uint)f2b(s.y) << 16);
    *(uint*)(out + node * D + lane * 2) = o;
}

// ============ fused dual GEMM + BN partials; W staged in LDS ============
__global__ __launch_bounds__(512, 4) void gemm_dual(const ushort* __restrict__ G,
                                                    const ushort* __restrict__ Wta, const float* __restrict__ ba,
                                                    const ushort* __restrict__ Wtb, const float* __restrict__ bb,
                                                    ushort* __restrict__ H, float4* __restrict__ stat, int nrows) {
    __shared__ ushort wbuf[16384];   // 32 KB swizzled W (Wa then Wb)
    __shared__ ushort tbuf[16384];   // 32 KB T then H, fragment layout
    __shared__ float4 red[8][64];
    char* wb = (char*)wbuf;
    char* tb = (char*)tbuf;

    const int tid = threadIdx.x;
    const int lane = tid & 63;
    const int wave = tid >> 6;          // 0..7
    const int lr = lane & 15;
    const int kg = lane >> 4;
    const int rloc = wave * 16 + lr;    // 0..127
    const int grow = blockIdx.x * 128 + rloc;
    const int growc = (grow > nrows - 1) ? (nrows - 1) : grow;
    const int wrow = lr * 256;
    const int wswz = (lr & 7) << 4;

    // ---- prefetch A fragments (coalesced global) ----
    const ushort* gp = G + growc * D + kg * 8;
    s16x8 af0 = *(const s16x8*)(gp);
    s16x8 af1 = *(const s16x8*)(gp + 32);
    s16x8 af2 = *(const s16x8*)(gp + 64);
    s16x8 af3 = *(const s16x8*)(gp + 96);

    // ---- stage Wa -> LDS (swizzled) ----
#pragma unroll
    for (int i = 0; i < 4; ++i) {
        int lin = i * 8192 + tid * 16;
        uint4 v = *(const uint4*)((const char*)Wta + lin);
        *(uint4*)(wb + SWZW(lin)) = v;
    }
    __syncthreads();

    f32x4 acc[8];
#pragma unroll
    for (int ct = 0; ct < 8; ++ct) acc[ct] = (f32x4)0.f;

    // ---- stage 1: acc = G @ Wa ----
#pragma unroll
    for (int ks = 0; ks < 4; ++ks) {
        s16x8 af = (ks == 0) ? af0 : (ks == 1) ? af1 : (ks == 2) ? af2 : af3;
        const int wofs = (kg * 16 + ks * 64) ^ wswz;
#pragma unroll
        for (int ct = 0; ct < 8; ++ct) {
            s16x8 a = *(const s16x8*)(wb + wrow + ct * 4096 + wofs);
            acc[ct] = __builtin_amdgcn_mfma_f32_16x16x32_bf16(a, af, acc[ct], 0, 0, 0);
        }
    }

    // ---- T = relu(acc + ba) -> tbuf ----
#pragma unroll
    for (int ct = 0; ct < 8; ++ct) {
        int k0 = ct * 16 + kg * 4;
        float4 bv = *(const float4*)(ba + k0);
        float o0 = fmaxf(acc[ct][0] + bv.x, 0.f);
        float o1 = fmaxf(acc[ct][1] + bv.y, 0.f);
        float o2 = fmaxf(acc[ct][2] + bv.z, 0.f);
        float o3 = fmaxf(acc[ct][3] + bv.w, 0.f);
        ushort pk[4] = {f2b(o0), f2b(o1), f2b(o2), f2b(o3)};
        int kb = k0 >> 3;
        int off = ((k0 >> 5) << 13) | ((kb & 3) << 11) | ((rloc ^ (kb & 7)) << 4) | ((k0 & 7) << 1);
        *(uint2*)(tb + off) = *(const uint2*)pk;
    }
    __syncthreads();

    // ---- stage Wb into wbuf ----
#pragma unroll
    for (int i = 0; i < 4; ++i) {
        int lin = i * 8192 + tid * 16;
        uint4 v = *(const uint4*)((const char*)Wtb + lin);
        *(uint4*)(wb + SWZW(lin)) = v;
    }
    // T fragments
    s16x8 bf[4];
#pragma unroll
    for (int ks = 0; ks < 4; ++ks) {
        int kb = ks * 4 + kg;
        bf[ks] = *(const s16x8*)(tb + ((ks << 13) | (kg << 11) | ((rloc ^ (kb & 7)) << 4)));
    }
    __syncthreads();

    // ---- stage 2: acc = T @ Wb ----
#pragma unroll
    for (int ct = 0; ct < 8; ++ct) acc[ct] = (f32x4)0.f;
#pragma unroll
    for (int ks = 0; ks < 4; ++ks) {
        const int wofs = (kg * 16 + ks * 64) ^ wswz;
#pragma unroll
        for (int ct = 0; ct < 8; ++ct) {
            s16x8 a = *(const s16x8*)(wb + wrow + ct * 4096 + wofs);
            acc[ct] = __builtin_amdgcn_mfma_f32_16x16x32_bf16(a, bf[ks], acc[ct], 0, 0, 0);
        }
    }

    // ---- H = acc + bb -> global + tbuf ----
#pragma unroll
    for (int ct = 0; ct < 8; ++ct) {
        int k0 = ct * 16 + kg * 4;
        float4 bv = *(const float4*)(bb + k0);
        uint2 pk2 = make_uint2(0u, 0u);
        if (grow < nrows) {
            float o0 = acc[ct][0] + bv.x;
            float o1 = acc[ct][1] + bv.y;
            float o2 = acc[ct][2] + bv.z;
            float o3 = acc[ct][3] + bv.w;
            ushort pk[4] = {f2b(o0), f2b(o1), f2b(o2), f2b(o3)};
            pk2 = *(const uint2*)pk;
            *(uint2*)(H + grow * D + k0) = pk2;
        }
        int kb = k0 >> 3;
        int off = ((k0 >> 5) << 13) | ((kb & 3) << 11) | ((rloc ^ (kb & 7)) << 4) | ((k0 & 7) << 1);
        *(uint2*)(tb + off) = pk2;
    }
    __syncthreads();

    // ---- column partials -> plain stores ----
    {
        int c2 = tid & 63;
        int rg = tid >> 6;
        int k = c2 * 2;
        int kb = k >> 3;
        int base = ((k >> 5) << 13) | ((kb & 3) << 11) | ((k & 7) << 1);
        float s0 = 0.f, q0 = 0.f, s1 = 0.f, q1 = 0.f;
#pragma unroll 4
        for (int i = 0; i < 16; ++i) {
            int row = rg * 16 + i;
            uint u = *(const uint*)(tb + base + ((row ^ (kb & 7)) << 4));
            float lo = blo(u), hi = bhi(u);
            s0 += lo; q0 += lo * lo; s1 += hi; q1 += hi * hi;
        }
        red[rg][c2] = make_float4(s0, q0, s1, q1);
    }
    __syncthreads();
    if (tid < 64) {
        float4 r0 = red[0][tid], r1 = red[1][tid], r2 = red[2][tid], r3 = red[3][tid];
        float4 r4 = red[4][tid], r5 = red[5][tid], r6 = red[6][tid], r7 = red[7][tid];
        float4 o;
        o.x = ((r0.x + r1.x) + (r2.x + r3.x)) + ((r4.x + r5.x) + (r6.x + r7.x));
        o.y = ((r0.y + r1.y) + (r2.y + r3.y)) + ((r4.y + r5.y) + (r6.y + r7.y));
        o.z = ((r0.z + r1.z) + (r2.z + r3.z)) + ((r4.z + r5.z) + (r6.z + r7.z));
        o.w = ((r0.w + r1.w) + (r2.w + r3.w)) + ((r4.w + r5.w) + (r6.w + r7.w));
        stat[blockIdx.x * 64 + tid] = o;
    }
}

// ============ parallel reduce of block partials + finalize scale/shift ============
__global__ __launch_bounds__(256) void bn_reduce(const float4* __restrict__ stat, int nblk,
                                                 const float* __restrict__ gamma, const float* __restrict__ beta,
                                                 float* __restrict__ scale, float* __restrict__ shift, int nrows) {
    const int f4 = blockIdx.x;      // 0..63
    const int t = threadIdx.x;
    float s0 = 0.f, q0 = 0.f, s1 = 0.f, q1 = 0.f;
    for (int b = t; b < nblk; b += 256) {
        float4 v = stat[b * 64 + f4];
        s0 += v.x; q0 += v.y; s1 += v.z; q1 += v.w;
    }
    __shared__ float4 red[256];
    red[t] = make_float4(s0, q0, s1, q1);
    __syncthreads();
    for (int off = 128; off >= 1; off >>= 1) {
        if (t < off) {
            float4 a = red[t], b = red[t + off];
            red[t] = make_float4(a.x + b.x, a.y + b.y, a.z + b.z, a.w + b.w);
        }
        __syncthreads();
    }
    if (t == 0) {
        float4 v = red[0];
        int f0 = 2 * f4, f1 = 2 * f4 + 1;
        double m0 = (double)v.x / nrows, var0 = (double)v.y / nrows - m0 * m0;
        double m1 = (double)v.z / nrows, var1 = (double)v.w / nrows - m1 * m1;
        float sc0 = gamma[f0] * rsqrtf((float)var0 + EPS);
        float sc1 = gamma[f1] * rsqrtf((float)var1 + EPS);
        scale[f0] = sc0; shift[f0] = beta[f0] - (float)m0 * sc0;
        scale[f1] = sc1; shift[f1] = beta[f1] - (float)m1 * sc1;
    }
}

// ============ pool: 16 rows/wave, partial sums via run-flush atomics ============
__global__ __launch_bounds__(256) void pool_partial(const ushort* __restrict__ h, const int* __restrict__ batch,
                                                    const float* __restrict__ scale, const float* __restrict__ shift,
                                                    float* __restrict__ pooled) {
    int wave = threadIdx.x >> 6;
    int lane = threadIdx.x & 63;
    int r0 = blockIdx.x * 64 + wave * 16;
    if (r0 >= NN) return;
    int f2 = lane * 2;
    float2 sc = *(const float2*)(scale + f2);
    float2 sh = *(const float2*)(shift + f2);
    float ax = 0.f, ay = 0.f;
    int cur = -1;
    int rend = r0 + 16; if (rend > NN) rend = NN;
    for (int r = r0; r < rend; ++r) {
        int g = batch[r];
        if (g != cur) {
            if (cur >= 0) {
                atomicAdd(&pooled[cur * D + f2], ax);
                atomicAdd(&pooled[cur * D + f2 + 1], ay);
            }
            cur = g; ax = 0.f; ay = 0.f;
        }
        uint u = *(const uint*)(h + r * D + f2);
        ax += fmaxf(fmaf(blo(u), sc.x, sh.x), 0.f);
        ay += fmaxf(fmaf(bhi(u), sc.y, sh.y), 0.f);
    }
    if (cur >= 0) {
        atomicAdd(&pooled[cur * D + f2], ax);
        atomicAdd(&pooled[cur * D + f2 + 1], ay);
    }
}

__device__ __forceinline__ int lower_bound_i(const int* a, int n, int v) {
    int lo = 0, hi = n;
    while (lo < hi) {
        int m = (lo + hi) >> 1;
        if (a[m] < v) lo = m + 1; else hi = m;
    }
    return lo;
}

__global__ __launch_bounds__(256) void head(const float* __restrict__ pooled, const int* __restrict__ batch,
                                            const float* __restrict__ wl, const float* __restrict__ bl,
                                            float* __restrict__ out) {
    int g = blockIdx.x * 256 + threadIdx.x;
    if (g >= NG) return;
    int lo = lower_bound_i(batch, NN, g);
    int hi = lower_bound_i(batch, NN, g + 1);
    float inv = 1.f / fmaxf((float)(hi - lo), 1.f);
    float logits[7];
#pragma unroll
    for (int c = 0; c < 7; ++c) logits[c] = bl[c];
    for (int k = 0; k < D; ++k) {
        float p = pooled[g * D + k] * inv;
#pragma unroll
        for (int c = 0; c < 7; ++c) logits[c] = fmaf(p, wl[k * 7 + c], logits[c]);
    }
    float m = logits[0];
#pragma unroll
    for (int c = 1; c < 7; ++c) m = fmaxf(m, logits[c]);
    float s = 0.f;
#pragma unroll
    for (int c = 0; c < 7; ++c) s += expf(logits[c] - m);
    float lse = m + logf(s);
#pragma unroll
    for (int c = 0; c < 7; ++c) out[g * 7 + c] = logits[c] - lse;
}

extern "C" void kernel_launch(void* const* d_in, const int* in_sizes, int n_in,
                              void* d_out, int out_size, void* d_ws, size_t ws_size,
                              hipStream_t stream) {
    const float* x   = (const float*)d_in[0];
    const float* w1a = (const float*)d_in[1];
    const float* b1a = (const float*)d_in[2];
    const float* w1b = (const float*)d_in[3];
    const float* b1b = (const float*)d_in[4];
    const float* g1  = (const float*)d_in[5];
    const float* be1 = (const float*)d_in[6];
    const float* w2a = (const float*)d_in[7];
    const float* b2a = (const float*)d_in[8];
    const float* w2b = (const float*)d_in[9];
    const float* b2b = (const float*)d_in[10];
    const float* g2  = (const float*)d_in[11];
    const float* be2 = (const float*)d_in[12];
    const float* wl  = (const float*)d_in[13];
    const float* bl  = (const float*)d_in[14];
    const int* ei    = (const int*)d_in[15];
    const int* batch = (const int*)d_in[16];
    float* out = (float*)d_out;

    const int* esrc = ei;
    const int* edst = ei + NE;

    char* ws = (char*)d_ws;
    ushort* B0 = (ushort*)(ws);                   // xb ; later G2
    ushort* B1 = (ushort*)(ws + 25600000);        // binbuf during build; then G1 / H2
    ushort* B2 = (ushort*)(ws + 51200000);        // H1
    uint* binbuf = (uint*)(ws + 25600000);        // 196*12288*4 = 9.6 MB (dead before gather1)
    int* slots   = (int*)(ws + 76800000);         // NN*64 ints
    int* deg     = (int*)(ws + 102400000);        // NN ints (written by drain)
    int* bincnt  = (int*)(ws + 102800000);        // 196 ints (memset)
    float* pooled = (float*)(ws + 102801024);     // 131072 B (memset)
    float* scale1 = (float*)(ws + 102932096);
    float* shift1 = scale1 + 128;
    float* scale2 = shift1 + 128;
    float* shift2 = scale2 + 128;
    ushort* Wt    = (ushort*)(ws + 102934144);
    float4* stat  = (float4*)(ws + 103065216);    // 782*64 float4
    ushort* Wt1a = Wt, *Wt1b = Wt + 16384, *Wt2a = Wt + 32768, *Wt2b = Wt + 49152;

    const int grid_prep = GRID_BIN + GRID_CAST + GRID_TW;    // 6532
    const int grid_pool = (NN + 63) / 64;                    // 1563
    const int grid_gath = (NN + 3) / 4;                      // 25000

    // memset covers bincnt + pooled: [102800000, 102932096)
    hipMemsetAsync(bincnt, 0, 132096, stream);

    prep1<<<grid_prep, 256, 0, stream>>>(esrc, edst, binbuf, bincnt, x, B0, w1a, w1b, w2a, w2b, Wt);
    drain<<<NBINS, 256, 0, stream>>>(binbuf, bincnt, deg, slots);

    // ---- layer 1 ----
    gather_slots<0><<<grid_gath, 256, 0, stream>>>(B1, B0, deg, slots, nullptr, nullptr);      // B1 = x+agg
    gemm_dual<<<GRID_GEMM, 512, 0, stream>>>(B1, Wt1a, b1a, Wt1b, b1b, B2, stat, NN);          // B2 = h1
    bn_reduce<<<64, 256, 0, stream>>>(stat, GRID_GEMM, g1, be1, scale1, shift1, NN);

    // ---- layer 2 (BN1+ReLU fused into gather) ----
    gather_slots<1><<<grid_gath, 256, 0, stream>>>(B0, B2, deg, slots, scale1, shift1);        // B0 = h1n+agg
    gemm_dual<<<GRID_GEMM, 512, 0, stream>>>(B0, Wt2a, b2a, Wt2b, b2b, B1, stat, NN);          // B1 = h2
    bn_reduce<<<64, 256, 0, stream>>>(stat, GRID_GEMM, g2, be2, scale2, shift2, NN);

    // ---- pool + head ----
    pool_partial<<<grid_pool, 256, 0, stream>>>(B1, batch, scale2, shift2, pooled);
    head<<<1, 256, 0, stream>>>(pooled, batch, wl, bl, out);
}

// Round 16
// 272.190 us; speedup vs baseline: 2.6221x; 1.0598x over previous
//
#include <hip/hip_runtime.h>
#include <math.h>

#define NN 100000
#define NE 1600000
#define NG 256
#define D 128
#define EPS 1e-5f
#define MAXDEG 64
#define NBINS 196           // ceil(NN/512)
#define BINSZ 512
#define BINCAP 12288
#define GRID_BIN 250
#define EPB_A 6400          // NE / 250
#define GRID_CAST 6250      // NN*D/8/256
#define GRID_TW 32
#define GRID_GEMM 782       // ceil(NN/128)

typedef __attribute__((ext_vector_type(8))) short s16x8;
typedef __attribute__((ext_vector_type(4))) float f32x4;

__device__ __forceinline__ ushort f2b(float f) {
    uint u = __float_as_uint(f);
    uint r = (u + 0x7fffu + ((u >> 16) & 1u)) >> 16;   // RNE
    return (ushort)r;
}
__device__ __forceinline__ float blo(uint u) { return __uint_as_float(u << 16); }
__device__ __forceinline__ float bhi(uint u) { return __uint_as_float(u & 0xFFFF0000u); }

// W-LDS byte swizzle: XOR row&7 into bits 4-6 of the intra-row offset (involution)
#define SWZW(lin) ((lin) ^ ((((lin) >> 8) & 7) << 4))

// ============ prep1: bin edges (packed u32) + cast x->bf16 + weight transpose ============
__global__ __launch_bounds__(256) void prep1(const int* __restrict__ esrc, const int* __restrict__ edst,
                                             uint* __restrict__ binbuf, int* __restrict__ bincnt,
                                             const float* __restrict__ x, ushort* __restrict__ xb,
                                             const float* __restrict__ w1a, const float* __restrict__ w1b,
                                             const float* __restrict__ w2a, const float* __restrict__ w2b,
                                             ushort* __restrict__ Wt) {
    int b = blockIdx.x;
    if (b < GRID_BIN) {
        __shared__ int cnt[NBINS], lbase[NBINS];
        const int ebase = b * EPB_A;
        for (int it = 0; it < 7; ++it) {
            for (int t = threadIdx.x; t < NBINS; t += 256) cnt[t] = 0;
            __syncthreads();
            int e = ebase + it * 1024 + threadIdx.x * 4;
            bool valid = (e < ebase + EPB_A);
            int4 s = make_int4(0, 0, 0, 0), d = make_int4(0, 0, 0, 0);
            if (valid) {
                s = *(const int4*)(esrc + e);
                d = *(const int4*)(edst + e);
            }
            int b0 = d.x >> 9, b1 = d.y >> 9, b2 = d.z >> 9, b3 = d.w >> 9;
            int o0 = 0, o1 = 0, o2 = 0, o3 = 0;
            if (valid) {
                o0 = atomicAdd(&cnt[b0], 1);
                o1 = atomicAdd(&cnt[b1], 1);
                o2 = atomicAdd(&cnt[b2], 1);
                o3 = atomicAdd(&cnt[b3], 1);
            }
            __syncthreads();
            for (int t = threadIdx.x; t < NBINS; t += 256)
                lbase[t] = (cnt[t] > 0) ? atomicAdd(&bincnt[t], cnt[t]) : 0;
            __syncthreads();
            if (valid) {
                uint p0 = (uint)(lbase[b0] + o0), p1 = (uint)(lbase[b1] + o1);
                uint p2 = (uint)(lbase[b2] + o2), p3 = (uint)(lbase[b3] + o3);
                if (p0 < BINCAP) binbuf[b0 * BINCAP + p0] = ((uint)(d.x & 511) << 17) | (uint)s.x;
                if (p1 < BINCAP) binbuf[b1 * BINCAP + p1] = ((uint)(d.y & 511) << 17) | (uint)s.y;
                if (p2 < BINCAP) binbuf[b2 * BINCAP + p2] = ((uint)(d.z & 511) << 17) | (uint)s.z;
                if (p3 < BINCAP) binbuf[b3 * BINCAP + p3] = ((uint)(d.w & 511) << 17) | (uint)s.w;
            }
        }
    } else if (b < GRID_BIN + GRID_CAST) {
        int i = (b - GRID_BIN) * 256 + threadIdx.x;
        if (i * 8 < NN * D) {
            float4 v0 = *(const float4*)(x + i * 8);
            float4 v1 = *(const float4*)(x + i * 8 + 4);
            ushort o[8] = {f2b(v0.x), f2b(v0.y), f2b(v0.z), f2b(v0.w),
                           f2b(v1.x), f2b(v1.y), f2b(v1.z), f2b(v1.w)};
            *(uint4*)(xb + i * 8) = *(uint4*)o;
        }
    } else {
        int by = b - GRID_BIN - GRID_CAST;       // 0..31
        int wsel = by >> 3, bx = by & 7;
        const float* W = (wsel == 0) ? w1a : (wsel == 1) ? w1b : (wsel == 2) ? w2a : w2b;
        ushort* T = Wt + wsel * 16384;
        for (int i = bx * 256 + threadIdx.x; i < 16384; i += 8 * 256) {
            int k = i >> 7, cc = i & 127;
            T[(cc << 7) | k] = f2b(W[i]);
        }
    }
}

// ============ drain: one block per bin; LDS counters; writes slots + deg ============
__global__ __launch_bounds__(256) void drain(const uint* __restrict__ binbuf, const int* __restrict__ bincnt,
                                             int* __restrict__ deg, int* __restrict__ slots) {
    const int bin = blockIdx.x;
    int n = bincnt[bin]; if (n > BINCAP) n = BINCAP;
    __shared__ int cur[BINSZ];
    cur[threadIdx.x] = 0;
    cur[threadIdx.x + 256] = 0;
    __syncthreads();
    const uint* bp = binbuf + bin * BINCAP;
    const int base = bin << 9;
    int i = threadIdx.x;
    for (; i + 768 < n; i += 1024) {
        uint u0 = bp[i], u1 = bp[i + 256], u2 = bp[i + 512], u3 = bp[i + 768];
        int l0 = u0 >> 17, l1 = u1 >> 17, l2 = u2 >> 17, l3 = u3 >> 17;
        int p0 = atomicAdd(&cur[l0], 1);
        int p1 = atomicAdd(&cur[l1], 1);
        int p2 = atomicAdd(&cur[l2], 1);
        int p3 = atomicAdd(&cur[l3], 1);
        slots[((base + l0) << 6) | (p0 & 63)] = (int)(u0 & 0x1FFFFu);
        slots[((base + l1) << 6) | (p1 & 63)] = (int)(u1 & 0x1FFFFu);
        slots[((base + l2) << 6) | (p2 & 63)] = (int)(u2 & 0x1FFFFu);
        slots[((base + l3) << 6) | (p3 & 63)] = (int)(u3 & 0x1FFFFu);
    }
    for (; i < n; i += 256) {
        uint u0 = bp[i];
        int l0 = u0 >> 17;
        int p0 = atomicAdd(&cur[l0], 1);
        slots[((base + l0) << 6) | (p0 & 63)] = (int)(u0 & 0x1FFFFu);
    }
    __syncthreads();
    int node = base + threadIdx.x;
    if (node < NN) deg[node] = cur[threadIdx.x];
    node += 256;
    if (node < NN) deg[node] = cur[threadIdx.x + 256];
}

// ============ gather, 16 rows in flight, scalar accumulators (36 VGPR), optional fused BN+ReLU ============
template <int FUSE_BN>
__global__ __launch_bounds__(256) void gather_slots(ushort* __restrict__ out, const ushort* __restrict__ feat,
                                                    const int* __restrict__ deg, const int* __restrict__ slots,
                                                    const float* __restrict__ scale, const float* __restrict__ shift) {
    int node = __builtin_amdgcn_readfirstlane(blockIdx.x * 4 + (threadIdx.x >> 6));
    if (node >= NN) return;
    int lane = threadIdx.x & 63;
    int n = deg[node];
    n = (n > MAXDEG) ? MAXDEG : n;
    const int* sl = slots + (node << 6);
    float scx = 1.f, scy = 1.f, shx = 0.f, shy = 0.f;
    if (FUSE_BN) {
        float2 sc = *(const float2*)(scale + lane * 2);
        float2 sh = *(const float2*)(shift + lane * 2);
        scx = sc.x; scy = sc.y; shx = sh.x; shy = sh.y;
    }
    uint ub = *(const uint*)(feat + node * D + lane * 2);
    float axv[8], ayv[8];
#pragma unroll
    for (int j = 0; j < 8; ++j) { axv[j] = 0.f; ayv[j] = 0.f; }
    if (FUSE_BN) {
        axv[0] = fmaxf(fmaf(blo(ub), scx, shx), 0.f);
        ayv[0] = fmaxf(fmaf(bhi(ub), scy, shy), 0.f);
    } else {
        axv[0] = blo(ub); ayv[0] = bhi(ub);
    }
    int e = 0;
    for (; e + 15 < n; e += 16) {
        uint u[16];
#pragma unroll
        for (int j = 0; j < 16; ++j) u[j] = *(const uint*)(feat + sl[e + j] * D + lane * 2);
#pragma unroll
        for (int j = 0; j < 16; ++j) {
            int j8 = j & 7;
            if (FUSE_BN) {
                axv[j8] += fmaxf(fmaf(blo(u[j]), scx, shx), 0.f);
                ayv[j8] += fmaxf(fmaf(bhi(u[j]), scy, shy), 0.f);
            } else {
                axv[j8] += blo(u[j]); ayv[j8] += bhi(u[j]);
            }
        }
    }
    for (; e + 7 < n; e += 8) {
        uint u[8];
#pragma unroll
        for (int j = 0; j < 8; ++j) u[j] = *(const uint*)(feat + sl[e + j] * D + lane * 2);
#pragma unroll
        for (int j = 0; j < 8; ++j) {
            if (FUSE_BN) {
                axv[j] += fmaxf(fmaf(blo(u[j]), scx, shx), 0.f);
                ayv[j] += fmaxf(fmaf(bhi(u[j]), scy, shy), 0.f);
            } else {
                axv[j] += blo(u[j]); ayv[j] += bhi(u[j]);
            }
        }
    }
    for (; e + 3 < n; e += 4) {
        uint u[4];
#pragma unroll
        for (int j = 0; j < 4; ++j) u[j] = *(const uint*)(feat + sl[e + j] * D + lane * 2);
#pragma unroll
        for (int j = 0; j < 4; ++j) {
            if (FUSE_BN) {
                axv[j] += fmaxf(fmaf(blo(u[j]), scx, shx), 0.f);
                ayv[j] += fmaxf(fmaf(bhi(u[j]), scy, shy), 0.f);
            } else {
                axv[j] += blo(u[j]); ayv[j] += bhi(u[j]);
            }
        }
    }
    for (; e < n; ++e) {
        uint u0 = *(const uint*)(feat + sl[e] * D + lane * 2);
        if (FUSE_BN) {
            axv[0] += fmaxf(fmaf(blo(u0), scx, shx), 0.f);
            ayv[0] += fmaxf(fmaf(bhi(u0), scy, shy), 0.f);
        } else {
            axv[0] += blo(u0); ayv[0] += bhi(u0);
        }
    }
    float ax = ((axv[0] + axv[1]) + (axv[2] + axv[3])) + ((axv[4] + axv[5]) + (axv[6] + axv[7]));
    float ay = ((ayv[0] + ayv[1]) + (ayv[2] + ayv[3])) + ((ayv[4] + ayv[5]) + (ayv[6] + ayv[7]));
    uint o = (uint)f2b(ax) | ((uint)f2b(ay) << 16);
    *(uint*)(out + node * D + lane * 2) = o;
}

// ============ fused dual GEMM + BN partials; W staged in LDS ============
__global__ __launch_bounds__(512, 4) void gemm_dual(const ushort* __restrict__ G,
                                                    const ushort* __restrict__ Wta, const float* __restrict__ ba,
                                                    const ushort* __restrict__ Wtb, const float* __restrict__ bb,
                                                    ushort* __restrict__ H, float4* __restrict__ stat, int nrows) {
    __shared__ ushort wbuf[16384];   // 32 KB swizzled W (Wa then Wb)
    __shared__ ushort tbuf[16384];   // 32 KB T then H, fragment layout
    __shared__ float4 red[8][64];
    char* wb = (char*)wbuf;
    char* tb = (char*)tbuf;

    const int tid = threadIdx.x;
    const int lane = tid & 63;
    const int wave = tid >> 6;          // 0..7
    const int lr = lane & 15;
    const int kg = lane >> 4;
    const int rloc = wave * 16 + lr;    // 0..127
    const int grow = blockIdx.x * 128 + rloc;
    const int growc = (grow > nrows - 1) ? (nrows - 1) : grow;
    const int wrow = lr * 256;
    const int wswz = (lr & 7) << 4;

    // ---- prefetch A fragments (coalesced global) ----
    const ushort* gp = G + growc * D + kg * 8;
    s16x8 af0 = *(const s16x8*)(gp);
    s16x8 af1 = *(const s16x8*)(gp + 32);
    s16x8 af2 = *(const s16x8*)(gp + 64);
    s16x8 af3 = *(const s16x8*)(gp + 96);

    // ---- stage Wa -> LDS (swizzled) ----
#pragma unroll
    for (int i = 0; i < 4; ++i) {
        int lin = i * 8192 + tid * 16;
        uint4 v = *(const uint4*)((const char*)Wta + lin);
        *(uint4*)(wb + SWZW(lin)) = v;
    }
    __syncthreads();

    f32x4 acc[8];
#pragma unroll
    for (int ct = 0; ct < 8; ++ct) acc[ct] = (f32x4)0.f;

    // ---- stage 1: acc = G @ Wa ----
#pragma unroll
    for (int ks = 0; ks < 4; ++ks) {
        s16x8 af = (ks == 0) ? af0 : (ks == 1) ? af1 : (ks == 2) ? af2 : af3;
        const int wofs = (kg * 16 + ks * 64) ^ wswz;
#pragma unroll
        for (int ct = 0; ct < 8; ++ct) {
            s16x8 a = *(const s16x8*)(wb + wrow + ct * 4096 + wofs);
            acc[ct] = __builtin_amdgcn_mfma_f32_16x16x32_bf16(a, af, acc[ct], 0, 0, 0);
        }
    }

    // ---- T = relu(acc + ba) -> tbuf ----
#pragma unroll
    for (int ct = 0; ct < 8; ++ct) {
        int k0 = ct * 16 + kg * 4;
        float4 bv = *(const float4*)(ba + k0);
        float o0 = fmaxf(acc[ct][0] + bv.x, 0.f);
        float o1 = fmaxf(acc[ct][1] + bv.y, 0.f);
        float o2 = fmaxf(acc[ct][2] + bv.z, 0.f);
        float o3 = fmaxf(acc[ct][3] + bv.w, 0.f);
        ushort pk[4] = {f2b(o0), f2b(o1), f2b(o2), f2b(o3)};
        int kb = k0 >> 3;
        int off = ((k0 >> 5) << 13) | ((kb & 3) << 11) | ((rloc ^ (kb & 7)) << 4) | ((k0 & 7) << 1);
        *(uint2*)(tb + off) = *(const uint2*)pk;
    }
    __syncthreads();

    // ---- stage Wb into wbuf ----
#pragma unroll
    for (int i = 0; i < 4; ++i) {
        int lin = i * 8192 + tid * 16;
        uint4 v = *(const uint4*)((const char*)Wtb + lin);
        *(uint4*)(wb + SWZW(lin)) = v;
    }
    // T fragments
    s16x8 bf[4];
#pragma unroll
    for (int ks = 0; ks < 4; ++ks) {
        int kb = ks * 4 + kg;
        bf[ks] = *(const s16x8*)(tb + ((ks << 13) | (kg << 11) | ((rloc ^ (kb & 7)) << 4)));
    }
    __syncthreads();

    // ---- stage 2: acc = T @ Wb ----
#pragma unroll
    for (int ct = 0; ct < 8; ++ct) acc[ct] = (f32x4)0.f;
#pragma unroll
    for (int ks = 0; ks < 4; ++ks) {
        const int wofs = (kg * 16 + ks * 64) ^ wswz;
#pragma unroll
        for (int ct = 0; ct < 8; ++ct) {
            s16x8 a = *(const s16x8*)(wb + wrow + ct * 4096 + wofs);
            acc[ct] = __builtin_amdgcn_mfma_f32_16x16x32_bf16(a, bf[ks], acc[ct], 0, 0, 0);
        }
    }

    // ---- H = acc + bb -> global + tbuf ----
#pragma unroll
    for (int ct = 0; ct < 8; ++ct) {
        int k0 = ct * 16 + kg * 4;
        float4 bv = *(const float4*)(bb + k0);
        uint2 pk2 = make_uint2(0u, 0u);
        if (grow < nrows) {
            float o0 = acc[ct][0] + bv.x;
            float o1 = acc[ct][1] + bv.y;
            float o2 = acc[ct][2] + bv.z;
            float o3 = acc[ct][3] + bv.w;
            ushort pk[4] = {f2b(o0), f2b(o1), f2b(o2), f2b(o3)};
            pk2 = *(const uint2*)pk;
            *(uint2*)(H + grow * D + k0) = pk2;
        }
        int kb = k0 >> 3;
        int off = ((k0 >> 5) << 13) | ((kb & 3) << 11) | ((rloc ^ (kb & 7)) << 4) | ((k0 & 7) << 1);
        *(uint2*)(tb + off) = pk2;
    }
    __syncthreads();

    // ---- column partials -> plain stores ----
    {
        int c2 = tid & 63;
        int rg = tid >> 6;
        int k = c2 * 2;
        int kb = k >> 3;
        int base = ((k >> 5) << 13) | ((kb & 3) << 11) | ((k & 7) << 1);
        float s0 = 0.f, q0 = 0.f, s1 = 0.f, q1 = 0.f;
#pragma unroll 4
        for (int i = 0; i < 16; ++i) {
            int row = rg * 16 + i;
            uint u = *(const uint*)(tb + base + ((row ^ (kb & 7)) << 4));
            float lo = blo(u), hi = bhi(u);
            s0 += lo; q0 += lo * lo; s1 += hi; q1 += hi * hi;
        }
        red[rg][c2] = make_float4(s0, q0, s1, q1);
    }
    __syncthreads();
    if (tid < 64) {
        float4 r0 = red[0][tid], r1 = red[1][tid], r2 = red[2][tid], r3 = red[3][tid];
        float4 r4 = red[4][tid], r5 = red[5][tid], r6 = red[6][tid], r7 = red[7][tid];
        float4 o;
        o.x = ((r0.x + r1.x) + (r2.x + r3.x)) + ((r4.x + r5.x) + (r6.x + r7.x));
        o.y = ((r0.y + r1.y) + (r2.y + r3.y)) + ((r4.y + r5.y) + (r6.y + r7.y));
        o.z = ((r0.z + r1.z) + (r2.z + r3.z)) + ((r4.z + r5.z) + (r6.z + r7.z));
        o.w = ((r0.w + r1.w) + (r2.w + r3.w)) + ((r4.w + r5.w) + (r6.w + r7.w));
        stat[blockIdx.x * 64 + tid] = o;
    }
}

// ============ parallel reduce of block partials + finalize scale/shift ============
__global__ __launch_bounds__(256) void bn_reduce(const float4* __restrict__ stat, int nblk,
                                                 const float* __restrict__ gamma, const float* __restrict__ beta,
                                                 float* __restrict__ scale, float* __restrict__ shift, int nrows) {
    const int f4 = blockIdx.x;      // 0..63
    const int t = threadIdx.x;
    float s0 = 0.f, q0 = 0.f, s1 = 0.f, q1 = 0.f;
    for (int b = t; b < nblk; b += 256) {
        float4 v = stat[b * 64 + f4];
        s0 += v.x; q0 += v.y; s1 += v.z; q1 += v.w;
    }
    __shared__ float4 red[256];
    red[t] = make_float4(s0, q0, s1, q1);
    __syncthreads();
    for (int off = 128; off >= 1; off >>= 1) {
        if (t < off) {
            float4 a = red[t], b = red[t + off];
            red[t] = make_float4(a.x + b.x, a.y + b.y, a.z + b.z, a.w + b.w);
        }
        __syncthreads();
    }
    if (t == 0) {
        float4 v = red[0];
        int f0 = 2 * f4, f1 = 2 * f4 + 1;
        double m0 = (double)v.x / nrows, var0 = (double)v.y / nrows - m0 * m0;
        double m1 = (double)v.z / nrows, var1 = (double)v.w / nrows - m1 * m1;
        float sc0 = gamma[f0] * rsqrtf((float)var0 + EPS);
        float sc1 = gamma[f1] * rsqrtf((float)var1 + EPS);
        scale[f0] = sc0; shift[f0] = beta[f0] - (float)m0 * sc0;
        scale[f1] = sc1; shift[f1] = beta[f1] - (float)m1 * sc1;
    }
}

// ============ pool: 16 rows/wave, partial sums via run-flush atomics ============
__global__ __launch_bounds__(256) void pool_partial(const ushort* __restrict__ h, const int* __restrict__ batch,
                                                    const float* __restrict__ scale, const float* __restrict__ shift,
                                                    float* __restrict__ pooled) {
    int wave = threadIdx.x >> 6;
    int lane = threadIdx.x & 63;
    int r0 = blockIdx.x * 64 + wave * 16;
    if (r0 >= NN) return;
    int f2 = lane * 2;
    float2 sc = *(const float2*)(scale + f2);
    float2 sh = *(const float2*)(shift + f2);
    float ax = 0.f, ay = 0.f;
    int cur = -1;
    int rend = r0 + 16; if (rend > NN) rend = NN;
    for (int r = r0; r < rend; ++r) {
        int g = batch[r];
        if (g != cur) {
            if (cur >= 0) {
                atomicAdd(&pooled[cur * D + f2], ax);
                atomicAdd(&pooled[cur * D + f2 + 1], ay);
            }
            cur = g; ax = 0.f; ay = 0.f;
        }
        uint u = *(const uint*)(h + r * D + f2);
        ax += fmaxf(fmaf(blo(u), sc.x, sh.x), 0.f);
        ay += fmaxf(fmaf(bhi(u), sc.y, sh.y), 0.f);
    }
    if (cur >= 0) {
        atomicAdd(&pooled[cur * D + f2], ax);
        atomicAdd(&pooled[cur * D + f2 + 1], ay);
    }
}

__device__ __forceinline__ int lower_bound_i(const int* a, int n, int v) {
    int lo = 0, hi = n;
    while (lo < hi) {
        int m = (lo + hi) >> 1;
        if (a[m] < v) lo = m + 1; else hi = m;
    }
    return lo;
}

__global__ __launch_bounds__(256) void head(const float* __restrict__ pooled, const int* __restrict__ batch,
                                            const float* __restrict__ wl, const float* __restrict__ bl,
                                            float* __restrict__ out) {
    int g = blockIdx.x * 256 + threadIdx.x;
    if (g >= NG) return;
    int lo = lower_bound_i(batch, NN, g);
    int hi = lower_bound_i(batch, NN, g + 1);
    float inv = 1.f / fmaxf((float)(hi - lo), 1.f);
    float logits[7];
#pragma unroll
    for (int c = 0; c < 7; ++c) logits[c] = bl[c];
    for (int k = 0; k < D; ++k) {
        float p = pooled[g * D + k] * inv;
#pragma unroll
        for (int c = 0; c < 7; ++c) logits[c] = fmaf(p, wl[k * 7 + c], logits[c]);
    }
    float m = logits[0];
#pragma unroll
    for (int c = 1; c < 7; ++c) m = fmaxf(m, logits[c]);
    float s = 0.f;
#pragma unroll
    for (int c = 0; c < 7; ++c) s += expf(logits[c] - m);
    float lse = m + logf(s);
#pragma unroll
    for (int c = 0; c < 7; ++c) out[g * 7 + c] = logits[c] - lse;
}

extern "C" void kernel_launch(void* const* d_in, const int* in_sizes, int n_in,
                              void* d_out, int out_size, void* d_ws, size_t ws_size,
                              hipStream_t stream) {
    const float* x   = (const float*)d_in[0];
    const float* w1a = (const float*)d_in[1];
    const float* b1a = (const float*)d_in[2];
    const float* w1b = (const float*)d_in[3];
    const float* b1b = (const float*)d_in[4];
    const float* g1  = (const float*)d_in[5];
    const float* be1 = (const float*)d_in[6];
    const float* w2a = (const float*)d_in[7];
    const float* b2a = (const float*)d_in[8];
    const float* w2b = (const float*)d_in[9];
    const float* b2b = (const float*)d_in[10];
    const float* g2  = (const float*)d_in[11];
    const float* be2 = (const float*)d_in[12];
    const float* wl  = (const float*)d_in[13];
    const float* bl  = (const float*)d_in[14];
    const int* ei    = (const int*)d_in[15];
    const int* batch = (const int*)d_in[16];
    float* out = (float*)d_out;

    const int* esrc = ei;
    const int* edst = ei + NE;

    char* ws = (char*)d_ws;
    ushort* B0 = (ushort*)(ws);                   // xb ; later G2
    ushort* B1 = (ushort*)(ws + 25600000);        // binbuf during build; then G1 / H2
    ushort* B2 = (ushort*)(ws + 51200000);        // H1
    uint* binbuf = (uint*)(ws + 25600000);        // 196*12288*4 = 9.6 MB (dead before gather1)
    int* slots   = (int*)(ws + 76800000);         // NN*64 ints
    int* deg     = (int*)(ws + 102400000);        // NN ints (written by drain)
    int* bincnt  = (int*)(ws + 102800000);        // 196 ints (memset)
    float* pooled = (float*)(ws + 102801024);     // 131072 B (memset)
    float* scale1 = (float*)(ws + 102932096);
    float* shift1 = scale1 + 128;
    float* scale2 = shift1 + 128;
    float* shift2 = scale2 + 128;
    ushort* Wt    = (ushort*)(ws + 102934144);
    float4* stat  = (float4*)(ws + 103065216);    // 782*64 float4
    ushort* Wt1a = Wt, *Wt1b = Wt + 16384, *Wt2a = Wt + 32768, *Wt2b = Wt + 49152;

    const int grid_prep = GRID_BIN + GRID_CAST + GRID_TW;    // 6532
    const int grid_pool = (NN + 63) / 64;                    // 1563
    const int grid_gath = (NN + 3) / 4;                      // 25000

    // memset covers bincnt + pooled: [102800000, 102932096)
    hipMemsetAsync(bincnt, 0, 132096, stream);

    prep1<<<grid_prep, 256, 0, stream>>>(esrc, edst, binbuf, bincnt, x, B0, w1a, w1b, w2a, w2b, Wt);
    drain<<<NBINS, 256, 0, stream>>>(binbuf, bincnt, deg, slots);

    // ---- layer 1 ----
    gather_slots<0><<<grid_gath, 256, 0, stream>>>(B1, B0, deg, slots, nullptr, nullptr);      // B1 = x+agg
    gemm_dual<<<GRID_GEMM, 512, 0, stream>>>(B1, Wt1a, b1a, Wt1b, b1b, B2, stat, NN);          // B2 = h1
    bn_reduce<<<64, 256, 0, stream>>>(stat, GRID_GEMM, g1, be1, scale1, shift1, NN);

    // ---- layer 2 (BN1+ReLU fused into gather) ----
    gather_slots<1><<<grid_gath, 256, 0, stream>>>(B0, B2, deg, slots, scale1, shift1);        // B0 = h1n+agg
    gemm_dual<<<GRID_GEMM, 512, 0, stream>>>(B0, Wt2a, b2a, Wt2b, b2b, B1, stat, NN);          // B1 = h2
    bn_reduce<<<64, 256, 0, stream>>>(stat, GRID_GEMM, g2, be2, scale2, shift2, NN);

    // ---- pool + head ----
    pool_partial<<<grid_pool, 256, 0, stream>>>(B1, batch, scale2, shift2, pooled);
    head<<<1, 256, 0, stream>>>(pooled, batch, wl, bl, out);
}